// Round 10
// baseline (351.728 us; speedup 1.0000x reference)
//
#include <hip/hip_runtime.h>
#include <hip/hip_bf16.h>

// Problem constants
constexpr int N_  = 50000;
constexpr int E_  = 800000;
constexpr int ET_ = 850000;   // edges + self loops
constexpr float NEG_SLOPE = 0.2f;

constexpr int SCAN_NB = (N_ + 255) / 256;   // 196 scan blocks

__device__ inline void edge_sd(int e, const int* __restrict__ ei, int& s, int& d) {
    if (e < E_) { s = ei[e]; d = ei[E_ + e]; }
    else        { s = e - E_; d = s; }
}

__device__ inline float leaky(float v) { return fmaxf(v, NEG_SLOPE * v); }

__device__ inline void fma4(float4& a, float s, const float4& w) {
    a.x = fmaf(s, w.x, a.x); a.y = fmaf(s, w.y, a.y);
    a.z = fmaf(s, w.z, a.z); a.w = fmaf(s, w.w, a.w);
}

// bf16 round-to-nearest-even (matches __float2bfloat16)
__device__ inline unsigned bf16rn(float f) {
    union { float f; unsigned u; } v; v.f = f;
    return (v.u + 0x7fffu + ((v.u >> 16) & 1u)) >> 16;
}
__device__ inline unsigned pack2(float lo, float hi) {
    return bf16rn(lo) | (bf16rn(hi) << 16);
}
__device__ inline float2 unpack2(unsigned u) {
    return make_float2(__uint_as_float(u << 16), __uint_as_float(u & 0xffff0000u));
}

// ======================= CSR build (dst-sorted) =======================
__global__ __launch_bounds__(256) void hist_kernel(
        const int* __restrict__ ei, int* __restrict__ count, int* __restrict__ off) {
    int e = blockIdx.x * 256 + threadIdx.x;
    if (e >= ET_) return;
    int s, d; edge_sd(e, ei, s, d);
    off[e] = atomicAdd(&count[d], 1);
}

// ---- 3-kernel parallel exclusive scan of count[N_] -> start[N_] ----
__global__ __launch_bounds__(256) void scan_partial(
        const int* __restrict__ count, int* __restrict__ bsum) {
    __shared__ int red[256];
    int t = threadIdx.x;
    int i = blockIdx.x * 256 + t;
    red[t] = (i < N_) ? count[i] : 0;
    __syncthreads();
    #pragma unroll
    for (int o = 128; o > 0; o >>= 1) {
        if (t < o) red[t] += red[t + o];
        __syncthreads();
    }
    if (t == 0) bsum[blockIdx.x] = red[0];
}

__global__ __launch_bounds__(256) void scan_top(
        const int* __restrict__ bsum, int* __restrict__ bstart) {
    __shared__ int buf[256];
    int t = threadIdx.x;
    int v = (t < SCAN_NB) ? bsum[t] : 0;
    buf[t] = v;
    __syncthreads();
    #pragma unroll
    for (int o = 1; o < 256; o <<= 1) {
        int add = (t >= o) ? buf[t - o] : 0;
        __syncthreads();
        buf[t] += add;
        __syncthreads();
    }
    if (t < SCAN_NB) bstart[t] = buf[t] - v;   // exclusive
}

__global__ __launch_bounds__(256) void scan_final(
        const int* __restrict__ count, const int* __restrict__ bstart,
        int* __restrict__ start) {
    __shared__ int buf[256];
    int t = threadIdx.x;
    int i = blockIdx.x * 256 + t;
    int v = (i < N_) ? count[i] : 0;
    buf[t] = v;
    __syncthreads();
    #pragma unroll
    for (int o = 1; o < 256; o <<= 1) {
        int add = (t >= o) ? buf[t - o] : 0;
        __syncthreads();
        buf[t] += add;
        __syncthreads();
    }
    if (i < N_) start[i] = bstart[blockIdx.x] + buf[t] - v;
}

__global__ __launch_bounds__(256) void scatter_kernel(
        const int* __restrict__ ei, const int* __restrict__ start,
        const int* __restrict__ off, int* __restrict__ csr_src) {
    int e = blockIdx.x * 256 + threadIdx.x;
    if (e >= ET_) return;
    int s, d; edge_sd(e, ei, s, d);
    csr_src[start[d] + off[e]] = s;
}

// ======================= layer 1 node transforms =======================
// 64 rows x 256 out-cols per block; thread: 8 rows x (4 Wl + 4 Wr cols),
// 64 accs. W double-buffered in registers (8 float4 prefetch) so L2 latency
// hides behind the 256 FMAs per k-quad. launch_bounds(256,2): VGPR cap 256.
__global__ __launch_bounds__(256, 2) void gemm1(
        const float* __restrict__ x,
        const float* __restrict__ Wl, const float* __restrict__ Wr,
        const float* __restrict__ bl, const float* __restrict__ br,
        unsigned* __restrict__ xl1b, float* __restrict__ xr1) {
    __shared__ float xs[64 * 128];          // 32 KB
    const int tid = threadIdx.x;
    const int n0  = blockIdx.x * 64;
    {   // stage 64 rows, coalesced float4 (8 per thread)
        int r   = tid >> 2;                 // 0..63
        int row = n0 + r; if (row >= N_) row = N_ - 1;
        const float4* src = (const float4*)(x + (size_t)row * 128);
        float4* dst = (float4*)(xs + r * 128);
        int c0 = tid & 3;
        #pragma unroll
        for (int i = 0; i < 8; ++i)
            dst[c0 + 4 * i] = src[c0 + 4 * i];
    }
    __syncthreads();
    const int g = tid >> 5;                 // row group 0..7 (8 rows each)
    const int t = tid & 31;                 // col-quad: cols 4t..4t+3
    const float* __restrict__ rows = xs + g * 8 * 128;
    float4 accl[8], accr[8];
    #pragma unroll
    for (int r = 0; r < 8; ++r) {
        accl[r] = make_float4(0.f, 0.f, 0.f, 0.f);
        accr[r] = make_float4(0.f, 0.f, 0.f, 0.f);
    }
    float4 wl[4], wr[4];
    #pragma unroll
    for (int q = 0; q < 4; ++q) {
        wl[q] = *(const float4*)(Wl + (size_t)q * 128 + 4 * t);
        wr[q] = *(const float4*)(Wr + (size_t)q * 128 + 4 * t);
    }
    #pragma unroll 2
    for (int k = 0; k < 128; k += 4) {
        int kn = (k + 4 < 128) ? k + 4 : k;   // harmless reload on last iter
        float4 nl[4], nr[4];
        #pragma unroll
        for (int q = 0; q < 4; ++q) {
            nl[q] = *(const float4*)(Wl + (size_t)(kn + q) * 128 + 4 * t);
            nr[q] = *(const float4*)(Wr + (size_t)(kn + q) * 128 + 4 * t);
        }
        #pragma unroll
        for (int r = 0; r < 8; ++r) {
            float4 xv = *(const float4*)(rows + r * 128 + k);
            fma4(accl[r], xv.x, wl[0]); fma4(accl[r], xv.y, wl[1]);
            fma4(accl[r], xv.z, wl[2]); fma4(accl[r], xv.w, wl[3]);
            fma4(accr[r], xv.x, wr[0]); fma4(accr[r], xv.y, wr[1]);
            fma4(accr[r], xv.z, wr[2]); fma4(accr[r], xv.w, wr[3]);
        }
        #pragma unroll
        for (int q = 0; q < 4; ++q) { wl[q] = nl[q]; wr[q] = nr[q]; }
    }
    float4 bvl = *(const float4*)(bl + 4 * t);
    float4 bvr = *(const float4*)(br + 4 * t);
    const int rbase = n0 + g * 8;
    #pragma unroll
    for (int r = 0; r < 8; ++r) {
        int row = rbase + r;
        if (row >= N_) continue;
        float4 vl = accl[r];
        vl.x += bvl.x; vl.y += bvl.y; vl.z += bvl.z; vl.w += bvl.w;
        uint2 pk;
        pk.x = pack2(vl.x, vl.y);
        pk.y = pack2(vl.z, vl.w);
        *(uint2*)(xl1b + (size_t)row * 64 + 2 * t) = pk;
        float4 vr = accr[r];
        vr.x += bvr.x; vr.y += bvr.y; vr.z += bvr.z; vr.w += bvr.w;
        *(float4*)(xr1 + (size_t)row * 128 + 4 * t) = vr;
    }
}

// ====== layer 1 fused attention: ONE wave per node, bf16-pair gathers ======
__global__ __launch_bounds__(256) void fused1(
        const int* __restrict__ csr_src, const int* __restrict__ start,
        const int* __restrict__ count,
        const unsigned* __restrict__ xl1b, const float* __restrict__ xr1,
        const float* __restrict__ att, const float* __restrict__ bias1,
        float* __restrict__ hout) {
    int t = blockIdx.x * 256 + threadIdx.x;
    int n = __builtin_amdgcn_readfirstlane(t >> 6);   // wave-uniform node id
    int lane = t & 63;
    if (n >= N_) return;
    float2 xr = *(const float2*)(xr1 + (size_t)n * 128 + 2 * lane);
    float2 av = *(const float2*)(att + 2 * lane);
    int p0 = __builtin_amdgcn_readfirstlane(start[n]);
    int p1 = p0 + __builtin_amdgcn_readfirstlane(count[n]);
    float2 acc = make_float2(0.f, 0.f);
    float l = 0.f;
    for (int p = p0; p < p1; p += 4) {
        int q1 = p + 1 < p1 ? p + 1 : p1 - 1;
        int q2 = p + 2 < p1 ? p + 2 : p1 - 1;
        int q3 = p + 3 < p1 ? p + 3 : p1 - 1;
        int s0 = __builtin_amdgcn_readfirstlane(csr_src[p]);
        int s1 = __builtin_amdgcn_readfirstlane(csr_src[q1]);
        int s2 = __builtin_amdgcn_readfirstlane(csr_src[q2]);
        int s3 = __builtin_amdgcn_readfirstlane(csr_src[q3]);
        float2 x0 = unpack2(xl1b[(size_t)s0 * 64 + lane]);
        float2 x1 = unpack2(xl1b[(size_t)s1 * 64 + lane]);
        float2 x2 = unpack2(xl1b[(size_t)s2 * 64 + lane]);
        float2 x3 = unpack2(xl1b[(size_t)s3 * 64 + lane]);
        float a0 = fmaf(leaky(x0.x + xr.x), av.x, leaky(x0.y + xr.y) * av.y);
        float a1 = fmaf(leaky(x1.x + xr.x), av.x, leaky(x1.y + xr.y) * av.y);
        float a2 = fmaf(leaky(x2.x + xr.x), av.x, leaky(x2.y + xr.y) * av.y);
        float a3 = fmaf(leaky(x3.x + xr.x), av.x, leaky(x3.y + xr.y) * av.y);
        a0 += __shfl_xor(a0, 1); a1 += __shfl_xor(a1, 1);
        a2 += __shfl_xor(a2, 1); a3 += __shfl_xor(a3, 1);
        a0 += __shfl_xor(a0, 2); a1 += __shfl_xor(a1, 2);
        a2 += __shfl_xor(a2, 2); a3 += __shfl_xor(a3, 2);
        a0 += __shfl_xor(a0, 4); a1 += __shfl_xor(a1, 4);
        a2 += __shfl_xor(a2, 4); a3 += __shfl_xor(a3, 4);
        float w0 = __expf(a0);
        float w1 = p + 1 < p1 ? __expf(a1) : 0.f;
        float w2 = p + 2 < p1 ? __expf(a2) : 0.f;
        float w3 = p + 3 < p1 ? __expf(a3) : 0.f;
        acc.x = fmaf(w0, x0.x, acc.x); acc.y = fmaf(w0, x0.y, acc.y); l += w0;
        acc.x = fmaf(w1, x1.x, acc.x); acc.y = fmaf(w1, x1.y, acc.y); l += w1;
        acc.x = fmaf(w2, x2.x, acc.x); acc.y = fmaf(w2, x2.y, acc.y); l += w2;
        acc.x = fmaf(w3, x3.x, acc.x); acc.y = fmaf(w3, x3.y, acc.y); l += w3;
    }
    float2 bv = *(const float2*)(bias1 + 2 * lane);
    float vx = acc.x / l + bv.x;
    float vy = acc.y / l + bv.y;
    float2 o;
    o.x = vx > 0.f ? vx : (__expf(vx) - 1.f);
    o.y = vy > 0.f ? vy : (__expf(vy) - 1.f);
    *(float2*)(hout + (size_t)n * 128 + 2 * lane) = o;
}

// ======================= layer 2 node transforms =======================
// 64 rows x 128 out-cols per block; thread: 8 rows x 4 cols of ONE W matrix
// (32 accs), W register double-buffer, bf16 pack for the xl2 half.
__global__ __launch_bounds__(256, 2) void gemm2(
        const float* __restrict__ hbuf,
        const float* __restrict__ Wl, const float* __restrict__ Wr,
        const float* __restrict__ bl, const float* __restrict__ br,
        unsigned* __restrict__ xl2b, float* __restrict__ xr2) {
    __shared__ float hs[64 * 128];          // 32 KB
    const int tid = threadIdx.x;
    const int n0  = blockIdx.x * 64;
    {   // stage 64 rows, coalesced float4 (8 per thread)
        int r   = tid >> 2;                 // 0..63
        int row = n0 + r; if (row >= N_) row = N_ - 1;
        const float4* src = (const float4*)(hbuf + (size_t)row * 128);
        float4* dst = (float4*)(hs + r * 128);
        int c0 = tid & 3;
        #pragma unroll
        for (int i = 0; i < 8; ++i)
            dst[c0 + 4 * i] = src[c0 + 4 * i];
    }
    __syncthreads();
    const int g  = tid >> 5;                // row group 0..7 (8 rows each)
    const int t  = tid & 31;
    const bool isR = (t & 16) != 0;         // 0: Wl -> xl2b, 1: Wr -> xr2
    const int tt = t & 15;                  // col-quad within the matrix
    const int col = 4 * tt;
    const float* __restrict__ W = isR ? Wr : Wl;
    const float* __restrict__ rows = hs + g * 8 * 128;
    float4 acc[8];
    #pragma unroll
    for (int r = 0; r < 8; ++r) acc[r] = make_float4(0.f, 0.f, 0.f, 0.f);
    float4 w[4];
    #pragma unroll
    for (int q = 0; q < 4; ++q)
        w[q] = *(const float4*)(W + (size_t)q * 64 + col);
    #pragma unroll 2
    for (int k = 0; k < 128; k += 4) {
        int kn = (k + 4 < 128) ? k + 4 : k;
        float4 nw[4];
        #pragma unroll
        for (int q = 0; q < 4; ++q)
            nw[q] = *(const float4*)(W + (size_t)(kn + q) * 64 + col);
        #pragma unroll
        for (int r = 0; r < 8; ++r) {
            float4 xv = *(const float4*)(rows + r * 128 + k);
            fma4(acc[r], xv.x, w[0]); fma4(acc[r], xv.y, w[1]);
            fma4(acc[r], xv.z, w[2]); fma4(acc[r], xv.w, w[3]);
        }
        #pragma unroll
        for (int q = 0; q < 4; ++q) w[q] = nw[q];
    }
    const float* __restrict__ bp = isR ? br : bl;
    float4 bv = *(const float4*)(bp + col);
    const int rbase = n0 + g * 8;
    #pragma unroll
    for (int r = 0; r < 8; ++r) {
        int row = rbase + r;
        if (row >= N_) continue;
        float4 v = acc[r];
        v.x += bv.x; v.y += bv.y; v.z += bv.z; v.w += bv.w;
        if (isR) {
            *(float4*)(xr2 + (size_t)row * 64 + col) = v;
        } else {
            uint2 pk;
            pk.x = pack2(v.x, v.y);
            pk.y = pack2(v.z, v.w);
            *(uint2*)(xl2b + (size_t)row * 32 + 2 * tt) = pk;
        }
    }
}

// ====== layer 2 fused attention: one wave per node, TWO edges at a time ======
__global__ __launch_bounds__(256) void fused2(
        const int* __restrict__ csr_src, const int* __restrict__ start,
        const int* __restrict__ count,
        const unsigned* __restrict__ xl2b, const float* __restrict__ xr2,
        const float* __restrict__ att, const float* __restrict__ bias2,
        float* __restrict__ out) {
    int t = blockIdx.x * 256 + threadIdx.x;
    int n = __builtin_amdgcn_readfirstlane(t >> 6);   // wave-uniform node id
    int lane = t & 63;
    int half = lane >> 5;                 // which edge of the pair
    int lc   = lane & 31;                 // channel pair id
    if (n >= N_) return;
    float2 xr = *(const float2*)(xr2 + (size_t)n * 64 + 2 * lc);
    float2 av = *(const float2*)(att + 2 * lc);
    int p0 = __builtin_amdgcn_readfirstlane(start[n]);
    int p1 = p0 + __builtin_amdgcn_readfirstlane(count[n]);
    float2 acc = make_float2(0.f, 0.f);
    float l = 0.f;
    for (int p = p0; p < p1; p += 8) {
        #pragma unroll
        for (int u = 0; u < 4; ++u) {
            int pe = p + 2 * u + half;
            int pc = pe < p1 ? pe : p1 - 1;
            int s  = csr_src[pc];
            float2 xv = unpack2(xl2b[(size_t)s * 32 + lc]);
            float a = fmaf(leaky(xv.x + xr.x), av.x, leaky(xv.y + xr.y) * av.y);
            a += __shfl_xor(a, 1);
            a += __shfl_xor(a, 2);
            a += __shfl_xor(a, 4);
            a += __shfl_xor(a, 8);
            a += __shfl_xor(a, 16);
            float w = pe < p1 ? __expf(a) : 0.f;
            acc.x = fmaf(w, xv.x, acc.x);
            acc.y = fmaf(w, xv.y, acc.y);
            l += w;
        }
    }
    acc.x += __shfl_xor(acc.x, 32);
    acc.y += __shfl_xor(acc.y, 32);
    l     += __shfl_xor(l, 32);
    if (half == 0) {
        float2 bv = *(const float2*)(bias2 + 2 * lc);
        float2 o;
        o.x = acc.x / l + bv.x;
        o.y = acc.y / l + bv.y;
        *(float2*)(out + (size_t)n * 64 + 2 * lc) = o;
    }
}

extern "C" void kernel_launch(void* const* d_in, const int* in_sizes, int n_in,
                              void* d_out, int out_size, void* d_ws, size_t ws_size,
                              hipStream_t stream) {
    (void)in_sizes; (void)n_in; (void)out_size; (void)ws_size;
    const float* x     = (const float*)d_in[0];
    const int*   ei    = (const int*)d_in[1];
    const float* W1l   = (const float*)d_in[2];
    const float* b1l   = (const float*)d_in[3];
    const float* W1r   = (const float*)d_in[4];
    const float* b1r   = (const float*)d_in[5];
    const float* att1  = (const float*)d_in[6];
    const float* bias1 = (const float*)d_in[7];
    const float* W2l   = (const float*)d_in[8];
    const float* b2l   = (const float*)d_in[9];
    const float* W2r   = (const float*)d_in[10];
    const float* b2r   = (const float*)d_in[11];
    const float* att2  = (const float*)d_in[12];
    const float* bias2 = (const float*)d_in[13];
    float* out = (float*)d_out;

    // workspace layout
    float* xr1      = (float*)d_ws;                // 6,400,000 f
    float* hbuf     = xr1 + 6400000;               // 6,400,000 f
    unsigned* xl1b  = (unsigned*)(hbuf + 6400000); // 3,200,000 u (bf16 pairs)
    int* count   = (int*)(xl1b + 3200000);         //    50,000 i
    int* startp  = count + 50000;                  //    50,000 i
    int* off     = startp + 50000;                 //   850,000 i
    int* csr_src = off + 850000;                   //   850,000 i
    int* bsum    = csr_src + 850000;               //       256 i
    int* bstart  = bsum + 256;                     //       256 i
    unsigned* xl2b = xl1b;                         // alias: xl1b dead after fused1
    float* xr2     = xr1;                          // alias: xr1 dead after fused1

    hipMemsetAsync((void*)count, 0, 50000 * sizeof(int), stream);

    const int EB = (ET_ + 255) / 256;
    hist_kernel <<<EB, 256, 0, stream>>>(ei, count, off);
    scan_partial<<<SCAN_NB, 256, 0, stream>>>(count, bsum);
    scan_top    <<<1, 256, 0, stream>>>(bsum, bstart);
    scan_final  <<<SCAN_NB, 256, 0, stream>>>(count, bstart, startp);
    scatter_kernel<<<EB, 256, 0, stream>>>(ei, startp, off, csr_src);

    gemm1 <<<(N_ + 63) / 64, 256, 0, stream>>>(x, W1l, W1r, b1l, b1r, xl1b, xr1);
    fused1<<<(N_ * 64 + 255) / 256, 256, 0, stream>>>(csr_src, startp, count,
                                                      xl1b, xr1, att1, bias1, hbuf);

    gemm2 <<<(N_ + 63) / 64, 256, 0, stream>>>(hbuf, W2l, W2r, b2l, b2r, xl2b, xr2);
    fused2<<<(N_ * 64 + 255) / 256, 256, 0, stream>>>(csr_src, startp, count,
                                                      xl2b, xr2, att2, bias2, out);
}

// Round 12
// 315.823 us; speedup vs baseline: 1.1137x; 1.1137x over previous
//
#include <hip/hip_runtime.h>
#include <hip/hip_bf16.h>

// Problem constants
constexpr int N_  = 50000;
constexpr int E_  = 800000;
constexpr int ET_ = 850000;   // edges + self loops
constexpr float NEG_SLOPE = 0.2f;

constexpr int SCAN_NB = (N_ + 255) / 256;   // 196 scan blocks

__device__ inline void edge_sd(int e, const int* __restrict__ ei, int& s, int& d) {
    if (e < E_) { s = ei[e]; d = ei[E_ + e]; }
    else        { s = e - E_; d = s; }
}

__device__ inline float leaky(float v) { return fmaxf(v, NEG_SLOPE * v); }

__device__ inline void fma4(float4& a, float s, const float4& w) {
    a.x = fmaf(s, w.x, a.x); a.y = fmaf(s, w.y, a.y);
    a.z = fmaf(s, w.z, a.z); a.w = fmaf(s, w.w, a.w);
}

// bf16 round-to-nearest-even (matches __float2bfloat16)
__device__ inline unsigned bf16rn(float f) {
    union { float f; unsigned u; } v; v.f = f;
    return (v.u + 0x7fffu + ((v.u >> 16) & 1u)) >> 16;
}
__device__ inline unsigned pack2(float lo, float hi) {
    return bf16rn(lo) | (bf16rn(hi) << 16);
}
__device__ inline float2 unpack2(unsigned u) {
    return make_float2(__uint_as_float(u << 16), __uint_as_float(u & 0xffff0000u));
}

// ======================= CSR build (dst-sorted) =======================
__global__ __launch_bounds__(256) void hist_kernel(
        const int* __restrict__ ei, int* __restrict__ count, int* __restrict__ off) {
    int e = blockIdx.x * 256 + threadIdx.x;
    if (e >= ET_) return;
    int s, d; edge_sd(e, ei, s, d);
    off[e] = atomicAdd(&count[d], 1);
}

__global__ __launch_bounds__(256) void scan_partial(
        const int* __restrict__ count, int* __restrict__ bsum) {
    __shared__ int red[256];
    int t = threadIdx.x;
    int i = blockIdx.x * 256 + t;
    red[t] = (i < N_) ? count[i] : 0;
    __syncthreads();
    #pragma unroll
    for (int o = 128; o > 0; o >>= 1) {
        if (t < o) red[t] += red[t + o];
        __syncthreads();
    }
    if (t == 0) bsum[blockIdx.x] = red[0];
}

__global__ __launch_bounds__(256) void scan_top(
        const int* __restrict__ bsum, int* __restrict__ bstart) {
    __shared__ int buf[256];
    int t = threadIdx.x;
    int v = (t < SCAN_NB) ? bsum[t] : 0;
    buf[t] = v;
    __syncthreads();
    #pragma unroll
    for (int o = 1; o < 256; o <<= 1) {
        int add = (t >= o) ? buf[t - o] : 0;
        __syncthreads();
        buf[t] += add;
        __syncthreads();
    }
    if (t < SCAN_NB) bstart[t] = buf[t] - v;   // exclusive
}

__global__ __launch_bounds__(256) void scan_final(
        const int* __restrict__ count, const int* __restrict__ bstart,
        int* __restrict__ start) {
    __shared__ int buf[256];
    int t = threadIdx.x;
    int i = blockIdx.x * 256 + t;
    int v = (i < N_) ? count[i] : 0;
    buf[t] = v;
    __syncthreads();
    #pragma unroll
    for (int o = 1; o < 256; o <<= 1) {
        int add = (t >= o) ? buf[t - o] : 0;
        __syncthreads();
        buf[t] += add;
        __syncthreads();
    }
    if (i < N_) start[i] = bstart[blockIdx.x] + buf[t] - v;
}

__global__ __launch_bounds__(256) void scatter_kernel(
        const int* __restrict__ ei, const int* __restrict__ start,
        const int* __restrict__ off, int* __restrict__ csr_src) {
    int e = blockIdx.x * 256 + threadIdx.x;
    if (e >= ET_) return;
    int s, d; edge_sd(e, ei, s, d);
    csr_src[start[d] + off[e]] = s;
}

// ======================= layer 1 node transforms =======================
// Round-8 structure (best measured: 66us): 64 rows x 256 out-cols per block,
// thread owns 8 rows x (4 Wl cols + 4 Wr cols) = 64 accs; no prefetch.
// Epilogue packs the xl half to bf16 pairs (r9/r10-validated pack).
__global__ __launch_bounds__(256) void gemm1(
        const float* __restrict__ x,
        const float* __restrict__ Wl, const float* __restrict__ Wr,
        const float* __restrict__ bl, const float* __restrict__ br,
        unsigned* __restrict__ xl1b, float* __restrict__ xr1) {
    __shared__ float xs[64 * 128];          // 32 KB
    const int tid = threadIdx.x;
    const int n0  = blockIdx.x * 64;
    {   // stage 64 rows, coalesced float4 (8 per thread)
        int r   = tid >> 2;                 // 0..63
        int row = n0 + r; if (row >= N_) row = N_ - 1;
        const float4* src = (const float4*)(x + (size_t)row * 128);
        float4* dst = (float4*)(xs + r * 128);
        int c0 = tid & 3;
        #pragma unroll
        for (int i = 0; i < 8; ++i)
            dst[c0 + 4 * i] = src[c0 + 4 * i];
    }
    __syncthreads();
    const int g = tid >> 5;                 // row group 0..7 (8 rows each)
    const int t = tid & 31;                 // col-quad: cols 4t..4t+3
    const float* __restrict__ rows = xs + g * 8 * 128;
    float4 accl[8], accr[8];
    #pragma unroll
    for (int r = 0; r < 8; ++r) {
        accl[r] = make_float4(0.f, 0.f, 0.f, 0.f);
        accr[r] = make_float4(0.f, 0.f, 0.f, 0.f);
    }
    for (int k = 0; k < 128; k += 4) {
        float4 wl0 = *(const float4*)(Wl + (size_t)(k+0)*128 + 4*t);
        float4 wl1 = *(const float4*)(Wl + (size_t)(k+1)*128 + 4*t);
        float4 wl2 = *(const float4*)(Wl + (size_t)(k+2)*128 + 4*t);
        float4 wl3 = *(const float4*)(Wl + (size_t)(k+3)*128 + 4*t);
        float4 wr0 = *(const float4*)(Wr + (size_t)(k+0)*128 + 4*t);
        float4 wr1 = *(const float4*)(Wr + (size_t)(k+1)*128 + 4*t);
        float4 wr2 = *(const float4*)(Wr + (size_t)(k+2)*128 + 4*t);
        float4 wr3 = *(const float4*)(Wr + (size_t)(k+3)*128 + 4*t);
        #pragma unroll
        for (int r = 0; r < 8; ++r) {
            float4 xv = *(const float4*)(rows + r * 128 + k);
            fma4(accl[r], xv.x, wl0); fma4(accl[r], xv.y, wl1);
            fma4(accl[r], xv.z, wl2); fma4(accl[r], xv.w, wl3);
            fma4(accr[r], xv.x, wr0); fma4(accr[r], xv.y, wr1);
            fma4(accr[r], xv.z, wr2); fma4(accr[r], xv.w, wr3);
        }
    }
    float4 bvl = *(const float4*)(bl + 4 * t);
    float4 bvr = *(const float4*)(br + 4 * t);
    const int rbase = n0 + g * 8;
    #pragma unroll
    for (int r = 0; r < 8; ++r) {
        int row = rbase + r;
        if (row >= N_) continue;
        float4 vl = accl[r];
        vl.x += bvl.x; vl.y += bvl.y; vl.z += bvl.z; vl.w += bvl.w;
        uint2 pk;
        pk.x = pack2(vl.x, vl.y);
        pk.y = pack2(vl.z, vl.w);
        *(uint2*)(xl1b + (size_t)row * 64 + 2 * t) = pk;
        float4 vr = accr[r];
        vr.x += bvr.x; vr.y += bvr.y; vr.z += bvr.z; vr.w += bvr.w;
        *(float4*)(xr1 + (size_t)row * 128 + 4 * t) = vr;
    }
}

// ====== layer 1 fused attention: ONE wave per node, bf16-pair gathers ======
// (r9/r10-validated) lane owns channels (2l, 2l+1); head = lane>>3.
// No max-subtraction: alphas are O(1); softmax is shift-invariant.
__global__ __launch_bounds__(256) void fused1(
        const int* __restrict__ csr_src, const int* __restrict__ start,
        const int* __restrict__ count,
        const unsigned* __restrict__ xl1b, const float* __restrict__ xr1,
        const float* __restrict__ att, const float* __restrict__ bias1,
        float* __restrict__ hout) {
    int t = blockIdx.x * 256 + threadIdx.x;
    int n = __builtin_amdgcn_readfirstlane(t >> 6);   // wave-uniform node id
    int lane = t & 63;
    if (n >= N_) return;
    float2 xr = *(const float2*)(xr1 + (size_t)n * 128 + 2 * lane);
    float2 av = *(const float2*)(att + 2 * lane);
    int p0 = __builtin_amdgcn_readfirstlane(start[n]);
    int p1 = p0 + __builtin_amdgcn_readfirstlane(count[n]);
    float2 acc = make_float2(0.f, 0.f);
    float l = 0.f;
    for (int p = p0; p < p1; p += 4) {
        int q1 = p + 1 < p1 ? p + 1 : p1 - 1;
        int q2 = p + 2 < p1 ? p + 2 : p1 - 1;
        int q3 = p + 3 < p1 ? p + 3 : p1 - 1;
        int s0 = __builtin_amdgcn_readfirstlane(csr_src[p]);
        int s1 = __builtin_amdgcn_readfirstlane(csr_src[q1]);
        int s2 = __builtin_amdgcn_readfirstlane(csr_src[q2]);
        int s3 = __builtin_amdgcn_readfirstlane(csr_src[q3]);
        float2 x0 = unpack2(xl1b[(size_t)s0 * 64 + lane]);
        float2 x1 = unpack2(xl1b[(size_t)s1 * 64 + lane]);
        float2 x2 = unpack2(xl1b[(size_t)s2 * 64 + lane]);
        float2 x3 = unpack2(xl1b[(size_t)s3 * 64 + lane]);
        float a0 = fmaf(leaky(x0.x + xr.x), av.x, leaky(x0.y + xr.y) * av.y);
        float a1 = fmaf(leaky(x1.x + xr.x), av.x, leaky(x1.y + xr.y) * av.y);
        float a2 = fmaf(leaky(x2.x + xr.x), av.x, leaky(x2.y + xr.y) * av.y);
        float a3 = fmaf(leaky(x3.x + xr.x), av.x, leaky(x3.y + xr.y) * av.y);
        a0 += __shfl_xor(a0, 1); a1 += __shfl_xor(a1, 1);
        a2 += __shfl_xor(a2, 1); a3 += __shfl_xor(a3, 1);
        a0 += __shfl_xor(a0, 2); a1 += __shfl_xor(a1, 2);
        a2 += __shfl_xor(a2, 2); a3 += __shfl_xor(a3, 2);
        a0 += __shfl_xor(a0, 4); a1 += __shfl_xor(a1, 4);
        a2 += __shfl_xor(a2, 4); a3 += __shfl_xor(a3, 4);
        float w0 = __expf(a0);
        float w1 = p + 1 < p1 ? __expf(a1) : 0.f;
        float w2 = p + 2 < p1 ? __expf(a2) : 0.f;
        float w3 = p + 3 < p1 ? __expf(a3) : 0.f;
        acc.x = fmaf(w0, x0.x, acc.x); acc.y = fmaf(w0, x0.y, acc.y); l += w0;
        acc.x = fmaf(w1, x1.x, acc.x); acc.y = fmaf(w1, x1.y, acc.y); l += w1;
        acc.x = fmaf(w2, x2.x, acc.x); acc.y = fmaf(w2, x2.y, acc.y); l += w2;
        acc.x = fmaf(w3, x3.x, acc.x); acc.y = fmaf(w3, x3.y, acc.y); l += w3;
    }
    float2 bv = *(const float2*)(bias1 + 2 * lane);
    float vx = acc.x / l + bv.x;
    float vy = acc.y / l + bv.y;
    float2 o;
    o.x = vx > 0.f ? vx : (__expf(vx) - 1.f);
    o.y = vy > 0.f ? vy : (__expf(vy) - 1.f);
    *(float2*)(hout + (size_t)n * 128 + 2 * lane) = o;
}

// ======================= layer 2 node transforms =======================
// 64 rows x 128 out-cols per block; thread: 8 rows x 4 cols of ONE W matrix
// (32 accs); straight loads, no prefetch (r10's prefetch hurt gemm1).
__global__ __launch_bounds__(256) void gemm2(
        const float* __restrict__ hbuf,
        const float* __restrict__ Wl, const float* __restrict__ Wr,
        const float* __restrict__ bl, const float* __restrict__ br,
        unsigned* __restrict__ xl2b, float* __restrict__ xr2) {
    __shared__ float hs[64 * 128];          // 32 KB
    const int tid = threadIdx.x;
    const int n0  = blockIdx.x * 64;
    {   // stage 64 rows, coalesced float4 (8 per thread)
        int r   = tid >> 2;                 // 0..63
        int row = n0 + r; if (row >= N_) row = N_ - 1;
        const float4* src = (const float4*)(hbuf + (size_t)row * 128);
        float4* dst = (float4*)(hs + r * 128);
        int c0 = tid & 3;
        #pragma unroll
        for (int i = 0; i < 8; ++i)
            dst[c0 + 4 * i] = src[c0 + 4 * i];
    }
    __syncthreads();
    const int g  = tid >> 5;                // row group 0..7 (8 rows each)
    const int t  = tid & 31;
    const bool isR = (t & 16) != 0;         // 0: Wl -> xl2b, 1: Wr -> xr2
    const int tt = t & 15;                  // col-quad within the matrix
    const int col = 4 * tt;
    const float* __restrict__ W = isR ? Wr : Wl;
    const float* __restrict__ rows = hs + g * 8 * 128;
    float4 acc[8];
    #pragma unroll
    for (int r = 0; r < 8; ++r) acc[r] = make_float4(0.f, 0.f, 0.f, 0.f);
    for (int k = 0; k < 128; k += 4) {
        float4 w0 = *(const float4*)(W + (size_t)(k+0) * 64 + col);
        float4 w1 = *(const float4*)(W + (size_t)(k+1) * 64 + col);
        float4 w2 = *(const float4*)(W + (size_t)(k+2) * 64 + col);
        float4 w3 = *(const float4*)(W + (size_t)(k+3) * 64 + col);
        #pragma unroll
        for (int r = 0; r < 8; ++r) {
            float4 xv = *(const float4*)(rows + r * 128 + k);
            fma4(acc[r], xv.x, w0); fma4(acc[r], xv.y, w1);
            fma4(acc[r], xv.z, w2); fma4(acc[r], xv.w, w3);
        }
    }
    const float* __restrict__ bp = isR ? br : bl;
    float4 bv = *(const float4*)(bp + col);
    const int rbase = n0 + g * 8;
    #pragma unroll
    for (int r = 0; r < 8; ++r) {
        int row = rbase + r;
        if (row >= N_) continue;
        float4 v = acc[r];
        v.x += bv.x; v.y += bv.y; v.z += bv.z; v.w += bv.w;
        if (isR) {
            *(float4*)(xr2 + (size_t)row * 64 + col) = v;
        } else {
            uint2 pk;
            pk.x = pack2(v.x, v.y);
            pk.y = pack2(v.z, v.w);
            *(uint2*)(xl2b + (size_t)row * 32 + 2 * tt) = pk;
        }
    }
}

// ====== layer 2 fused attention: one wave per node, TWO edges at a time ======
// (r9/r10-validated)
__global__ __launch_bounds__(256) void fused2(
        const int* __restrict__ csr_src, const int* __restrict__ start,
        const int* __restrict__ count,
        const unsigned* __restrict__ xl2b, const float* __restrict__ xr2,
        const float* __restrict__ att, const float* __restrict__ bias2,
        float* __restrict__ out) {
    int t = blockIdx.x * 256 + threadIdx.x;
    int n = __builtin_amdgcn_readfirstlane(t >> 6);   // wave-uniform node id
    int lane = t & 63;
    int half = lane >> 5;                 // which edge of the pair
    int lc   = lane & 31;                 // channel pair id
    if (n >= N_) return;
    float2 xr = *(const float2*)(xr2 + (size_t)n * 64 + 2 * lc);
    float2 av = *(const float2*)(att + 2 * lc);
    int p0 = __builtin_amdgcn_readfirstlane(start[n]);
    int p1 = p0 + __builtin_amdgcn_readfirstlane(count[n]);
    float2 acc = make_float2(0.f, 0.f);
    float l = 0.f;
    for (int p = p0; p < p1; p += 8) {
        #pragma unroll
        for (int u = 0; u < 4; ++u) {
            int pe = p + 2 * u + half;
            int pc = pe < p1 ? pe : p1 - 1;
            int s  = csr_src[pc];
            float2 xv = unpack2(xl2b[(size_t)s * 32 + lc]);
            float a = fmaf(leaky(xv.x + xr.x), av.x, leaky(xv.y + xr.y) * av.y);
            a += __shfl_xor(a, 1);
            a += __shfl_xor(a, 2);
            a += __shfl_xor(a, 4);
            a += __shfl_xor(a, 8);
            a += __shfl_xor(a, 16);
            float w = pe < p1 ? __expf(a) : 0.f;
            acc.x = fmaf(w, xv.x, acc.x);
            acc.y = fmaf(w, xv.y, acc.y);
            l += w;
        }
    }
    acc.x += __shfl_xor(acc.x, 32);
    acc.y += __shfl_xor(acc.y, 32);
    l     += __shfl_xor(l, 32);
    if (half == 0) {
        float2 bv = *(const float2*)(bias2 + 2 * lc);
        float2 o;
        o.x = acc.x / l + bv.x;
        o.y = acc.y / l + bv.y;
        *(float2*)(out + (size_t)n * 64 + 2 * lc) = o;
    }
}

extern "C" void kernel_launch(void* const* d_in, const int* in_sizes, int n_in,
                              void* d_out, int out_size, void* d_ws, size_t ws_size,
                              hipStream_t stream) {
    (void)in_sizes; (void)n_in; (void)out_size; (void)ws_size;
    const float* x     = (const float*)d_in[0];
    const int*   ei    = (const int*)d_in[1];
    const float* W1l   = (const float*)d_in[2];
    const float* b1l   = (const float*)d_in[3];
    const float* W1r   = (const float*)d_in[4];
    const float* b1r   = (const float*)d_in[5];
    const float* att1  = (const float*)d_in[6];
    const float* bias1 = (const float*)d_in[7];
    const float* W2l   = (const float*)d_in[8];
    const float* b2l   = (const float*)d_in[9];
    const float* W2r   = (const float*)d_in[10];
    const float* b2r   = (const float*)d_in[11];
    const float* att2  = (const float*)d_in[12];
    const float* bias2 = (const float*)d_in[13];
    float* out = (float*)d_out;

    // workspace layout (identical to rounds 9/10, which passed replay checks)
    float* xr1      = (float*)d_ws;                // 6,400,000 f
    float* hbuf     = xr1 + 6400000;               // 6,400,000 f
    unsigned* xl1b  = (unsigned*)(hbuf + 6400000); // 3,200,000 u (bf16 pairs)
    int* count   = (int*)(xl1b + 3200000);         //    50,000 i
    int* startp  = count + 50000;                  //    50,000 i
    int* off     = startp + 50000;                 //   850,000 i
    int* csr_src = off + 850000;                   //   850,000 i
    int* bsum    = csr_src + 850000;               //       256 i
    int* bstart  = bsum + 256;                     //       256 i
    unsigned* xl2b = xl1b;                         // alias: xl1b dead after fused1
    float* xr2     = xr1;                          // alias: xr1 dead after fused1

    hipMemsetAsync((void*)count, 0, 50000 * sizeof(int), stream);

    const int EB = (ET_ + 255) / 256;
    hist_kernel <<<EB, 256, 0, stream>>>(ei, count, off);
    scan_partial<<<SCAN_NB, 256, 0, stream>>>(count, bsum);
    scan_top    <<<1, 256, 0, stream>>>(bsum, bstart);
    scan_final  <<<SCAN_NB, 256, 0, stream>>>(count, bstart, startp);
    scatter_kernel<<<EB, 256, 0, stream>>>(ei, startp, off, csr_src);

    gemm1 <<<(N_ + 63) / 64, 256, 0, stream>>>(x, W1l, W1r, b1l, b1r, xl1b, xr1);
    fused1<<<(N_ * 64 + 255) / 256, 256, 0, stream>>>(csr_src, startp, count,
                                                      xl1b, xr1, att1, bias1, hbuf);

    gemm2 <<<(N_ + 63) / 64, 256, 0, stream>>>(hbuf, W2l, W2r, b2l, b2r, xl2b, xr2);
    fused2<<<(N_ * 64 + 255) / 256, 256, 0, stream>>>(csr_src, startp, count,
                                                      xl2b, xr2, att2, bias2, out);
}

// Round 13
// 288.106 us; speedup vs baseline: 1.2208x; 1.0962x over previous
//
#include <hip/hip_runtime.h>
#include <hip/hip_bf16.h>

// Problem constants
constexpr int N_  = 50000;
constexpr int E_  = 800000;
constexpr int ET_ = 850000;   // edges + self loops
constexpr float NEG_SLOPE = 0.2f;

constexpr int SCAN_NB = (N_ + 255) / 256;   // 196 scan blocks

typedef __attribute__((ext_vector_type(8))) short short8;   // 8 bf16 = 4 VGPRs
typedef __attribute__((ext_vector_type(4))) float f32x4;    // MFMA accumulator

__device__ inline void edge_sd(int e, const int* __restrict__ ei, int& s, int& d) {
    if (e < E_) { s = ei[e]; d = ei[E_ + e]; }
    else        { s = e - E_; d = s; }
}

__device__ inline float leaky(float v) { return fmaxf(v, NEG_SLOPE * v); }

__device__ inline void fma4(float4& a, float s, const float4& w) {
    a.x = fmaf(s, w.x, a.x); a.y = fmaf(s, w.y, a.y);
    a.z = fmaf(s, w.z, a.z); a.w = fmaf(s, w.w, a.w);
}

// bf16 round-to-nearest-even (matches __float2bfloat16)
__device__ inline unsigned bf16rn(float f) {
    union { float f; unsigned u; } v; v.f = f;
    return (v.u + 0x7fffu + ((v.u >> 16) & 1u)) >> 16;
}
__device__ inline unsigned pack2(float lo, float hi) {
    return bf16rn(lo) | (bf16rn(hi) << 16);
}
__device__ inline float2 unpack2(unsigned u) {
    return make_float2(__uint_as_float(u << 16), __uint_as_float(u & 0xffff0000u));
}

// ======================= CSR build (dst-sorted) =======================
__global__ __launch_bounds__(256) void hist_kernel(
        const int* __restrict__ ei, int* __restrict__ count, int* __restrict__ off) {
    int e = blockIdx.x * 256 + threadIdx.x;
    if (e >= ET_) return;
    int s, d; edge_sd(e, ei, s, d);
    off[e] = atomicAdd(&count[d], 1);
}

__global__ __launch_bounds__(256) void scan_partial(
        const int* __restrict__ count, int* __restrict__ bsum) {
    __shared__ int red[256];
    int t = threadIdx.x;
    int i = blockIdx.x * 256 + t;
    red[t] = (i < N_) ? count[i] : 0;
    __syncthreads();
    #pragma unroll
    for (int o = 128; o > 0; o >>= 1) {
        if (t < o) red[t] += red[t + o];
        __syncthreads();
    }
    if (t == 0) bsum[blockIdx.x] = red[0];
}

__global__ __launch_bounds__(256) void scan_top(
        const int* __restrict__ bsum, int* __restrict__ bstart) {
    __shared__ int buf[256];
    int t = threadIdx.x;
    int v = (t < SCAN_NB) ? bsum[t] : 0;
    buf[t] = v;
    __syncthreads();
    #pragma unroll
    for (int o = 1; o < 256; o <<= 1) {
        int add = (t >= o) ? buf[t - o] : 0;
        __syncthreads();
        buf[t] += add;
        __syncthreads();
    }
    if (t < SCAN_NB) bstart[t] = buf[t] - v;   // exclusive
}

__global__ __launch_bounds__(256) void scan_final(
        const int* __restrict__ count, const int* __restrict__ bstart,
        int* __restrict__ start) {
    __shared__ int buf[256];
    int t = threadIdx.x;
    int i = blockIdx.x * 256 + t;
    int v = (i < N_) ? count[i] : 0;
    buf[t] = v;
    __syncthreads();
    #pragma unroll
    for (int o = 1; o < 256; o <<= 1) {
        int add = (t >= o) ? buf[t - o] : 0;
        __syncthreads();
        buf[t] += add;
        __syncthreads();
    }
    if (i < N_) start[i] = bstart[blockIdx.x] + buf[t] - v;
}

__global__ __launch_bounds__(256) void scatter_kernel(
        const int* __restrict__ ei, const int* __restrict__ start,
        const int* __restrict__ off, int* __restrict__ csr_src) {
    int e = blockIdx.x * 256 + threadIdx.x;
    if (e >= ET_) return;
    int s, d; edge_sd(e, ei, s, d);
    csr_src[start[d] + off[e]] = s;
}

// ============ W1 -> B-fragment-swizzled bf16 (64 KB, aliased in hbuf) ============
// wsw[((ct*4+ks)*64 + lane)*8 + j] = bf16(W[k = ks*32 + (lane>>4)*8 + j]
//                                          [c = ct*16 + (lane&15)])
// ct 0..7 -> W1l cols 0..127; ct 8..15 -> W1r cols 0..127.
__global__ __launch_bounds__(256) void convert_w(
        const float* __restrict__ Wl, const float* __restrict__ Wr,
        unsigned short* __restrict__ wsw) {
    int tid = blockIdx.x * 256 + threadIdx.x;   // 0..32767
    if (tid >= 32768) return;
    int j    = tid & 7;
    int lane = (tid >> 3) & 63;
    int ks   = (tid >> 9) & 3;
    int ct   = tid >> 11;
    int k = ks * 32 + ((lane >> 4) & 3) * 8 + j;
    int c = ct * 16 + (lane & 15);
    float v = (c < 128) ? Wl[k * 128 + c] : Wr[k * 128 + (c - 128)];
    wsw[tid] = (unsigned short)bf16rn(v);
}

// ======================= layer 1 node transforms (MFMA) =======================
// Flat grid: 3125 blocks x 256 threads. Each wave: 16 rows x 4 col-tiles,
// A fragments (bf16-converted in-register from fp32 x) reused across tiles.
// Verified mappings (m89/m120): A[m=lane&15][k=(lane>>4)*8+j];
// C: col=lane&15, row=(lane>>4)*4+reg. No cross-lane ops; xl as bf16 singles.
__global__ __launch_bounds__(256) void gemm1_mfma(
        const float* __restrict__ x,
        const unsigned short* __restrict__ wsw,
        const float* __restrict__ bl, const float* __restrict__ br,
        unsigned short* __restrict__ xlu, float* __restrict__ xr1) {
    const int wave = threadIdx.x >> 6;
    const int lane = threadIdx.x & 63;
    const int n0 = blockIdx.x * 16;
    const int m = lane & 15;
    const int q = (lane >> 4) & 3;
    const float* __restrict__ arow = x + (size_t)(n0 + m) * 128 + q * 8;
    short8 afrag[4];
    #pragma unroll
    for (int ks = 0; ks < 4; ++ks) {
        float4 v0 = *(const float4*)(arow + ks * 32);
        float4 v1 = *(const float4*)(arow + ks * 32 + 4);
        short8 a;
        a[0] = (short)bf16rn(v0.x); a[1] = (short)bf16rn(v0.y);
        a[2] = (short)bf16rn(v0.z); a[3] = (short)bf16rn(v0.w);
        a[4] = (short)bf16rn(v1.x); a[5] = (short)bf16rn(v1.y);
        a[6] = (short)bf16rn(v1.z); a[7] = (short)bf16rn(v1.w);
        afrag[ks] = a;
    }
    #pragma unroll
    for (int i = 0; i < 4; ++i) {
        const int ct = wave * 4 + i;
        f32x4 acc = {0.f, 0.f, 0.f, 0.f};
        #pragma unroll
        for (int ks = 0; ks < 4; ++ks) {
            short8 b = *(const short8*)(wsw + ((size_t)(ct * 4 + ks) * 64 + lane) * 8);
            acc = __builtin_amdgcn_mfma_f32_16x16x32_bf16(afrag[ks], b, acc, 0, 0, 0);
        }
        const int col = ct * 16 + m;
        if (ct < 8) {
            float bias = bl[col];
            #pragma unroll
            for (int j = 0; j < 4; ++j) {
                int row = n0 + q * 4 + j;
                xlu[(size_t)row * 128 + col] = (unsigned short)bf16rn(acc[j] + bias);
            }
        } else {
            float bias = br[col - 128];
            #pragma unroll
            for (int j = 0; j < 4; ++j) {
                int row = n0 + q * 4 + j;
                xr1[(size_t)row * 128 + (col - 128)] = acc[j] + bias;
            }
        }
    }
}

// ====== layer 1 fused attention: ONE wave per node, bf16-pair gathers ======
// (r9/r10/r12-validated) lane owns channels (2l, 2l+1); head = lane>>3.
__global__ __launch_bounds__(256) void fused1(
        const int* __restrict__ csr_src, const int* __restrict__ start,
        const int* __restrict__ count,
        const unsigned* __restrict__ xl1b, const float* __restrict__ xr1,
        const float* __restrict__ att, const float* __restrict__ bias1,
        float* __restrict__ hout) {
    int t = blockIdx.x * 256 + threadIdx.x;
    int n = __builtin_amdgcn_readfirstlane(t >> 6);   // wave-uniform node id
    int lane = t & 63;
    if (n >= N_) return;
    float2 xr = *(const float2*)(xr1 + (size_t)n * 128 + 2 * lane);
    float2 av = *(const float2*)(att + 2 * lane);
    int p0 = __builtin_amdgcn_readfirstlane(start[n]);
    int p1 = p0 + __builtin_amdgcn_readfirstlane(count[n]);
    float2 acc = make_float2(0.f, 0.f);
    float l = 0.f;
    for (int p = p0; p < p1; p += 4) {
        int q1 = p + 1 < p1 ? p + 1 : p1 - 1;
        int q2 = p + 2 < p1 ? p + 2 : p1 - 1;
        int q3 = p + 3 < p1 ? p + 3 : p1 - 1;
        int s0 = __builtin_amdgcn_readfirstlane(csr_src[p]);
        int s1 = __builtin_amdgcn_readfirstlane(csr_src[q1]);
        int s2 = __builtin_amdgcn_readfirstlane(csr_src[q2]);
        int s3 = __builtin_amdgcn_readfirstlane(csr_src[q3]);
        float2 x0 = unpack2(xl1b[(size_t)s0 * 64 + lane]);
        float2 x1 = unpack2(xl1b[(size_t)s1 * 64 + lane]);
        float2 x2 = unpack2(xl1b[(size_t)s2 * 64 + lane]);
        float2 x3 = unpack2(xl1b[(size_t)s3 * 64 + lane]);
        float a0 = fmaf(leaky(x0.x + xr.x), av.x, leaky(x0.y + xr.y) * av.y);
        float a1 = fmaf(leaky(x1.x + xr.x), av.x, leaky(x1.y + xr.y) * av.y);
        float a2 = fmaf(leaky(x2.x + xr.x), av.x, leaky(x2.y + xr.y) * av.y);
        float a3 = fmaf(leaky(x3.x + xr.x), av.x, leaky(x3.y + xr.y) * av.y);
        a0 += __shfl_xor(a0, 1); a1 += __shfl_xor(a1, 1);
        a2 += __shfl_xor(a2, 1); a3 += __shfl_xor(a3, 1);
        a0 += __shfl_xor(a0, 2); a1 += __shfl_xor(a1, 2);
        a2 += __shfl_xor(a2, 2); a3 += __shfl_xor(a3, 2);
        a0 += __shfl_xor(a0, 4); a1 += __shfl_xor(a1, 4);
        a2 += __shfl_xor(a2, 4); a3 += __shfl_xor(a3, 4);
        float w0 = __expf(a0);
        float w1 = p + 1 < p1 ? __expf(a1) : 0.f;
        float w2 = p + 2 < p1 ? __expf(a2) : 0.f;
        float w3 = p + 3 < p1 ? __expf(a3) : 0.f;
        acc.x = fmaf(w0, x0.x, acc.x); acc.y = fmaf(w0, x0.y, acc.y); l += w0;
        acc.x = fmaf(w1, x1.x, acc.x); acc.y = fmaf(w1, x1.y, acc.y); l += w1;
        acc.x = fmaf(w2, x2.x, acc.x); acc.y = fmaf(w2, x2.y, acc.y); l += w2;
        acc.x = fmaf(w3, x3.x, acc.x); acc.y = fmaf(w3, x3.y, acc.y); l += w3;
    }
    float2 bv = *(const float2*)(bias1 + 2 * lane);
    float vx = acc.x / l + bv.x;
    float vy = acc.y / l + bv.y;
    float2 o;
    o.x = vx > 0.f ? vx : (__expf(vx) - 1.f);
    o.y = vy > 0.f ? vy : (__expf(vy) - 1.f);
    *(float2*)(hout + (size_t)n * 128 + 2 * lane) = o;
}

// ======================= layer 2 node transforms =======================
// (r12-validated) 64 rows x 128 out-cols; thread: 8 rows x 4 cols of one W.
__global__ __launch_bounds__(256) void gemm2(
        const float* __restrict__ hbuf,
        const float* __restrict__ Wl, const float* __restrict__ Wr,
        const float* __restrict__ bl, const float* __restrict__ br,
        unsigned* __restrict__ xl2b, float* __restrict__ xr2) {
    __shared__ float hs[64 * 128];          // 32 KB
    const int tid = threadIdx.x;
    const int n0  = blockIdx.x * 64;
    {   // stage 64 rows, coalesced float4 (8 per thread)
        int r   = tid >> 2;                 // 0..63
        int row = n0 + r; if (row >= N_) row = N_ - 1;
        const float4* src = (const float4*)(hbuf + (size_t)row * 128);
        float4* dst = (float4*)(hs + r * 128);
        int c0 = tid & 3;
        #pragma unroll
        for (int i = 0; i < 8; ++i)
            dst[c0 + 4 * i] = src[c0 + 4 * i];
    }
    __syncthreads();
    const int g  = tid >> 5;                // row group 0..7 (8 rows each)
    const int t  = tid & 31;
    const bool isR = (t & 16) != 0;         // 0: Wl -> xl2b, 1: Wr -> xr2
    const int tt = t & 15;                  // col-quad within the matrix
    const int col = 4 * tt;
    const float* __restrict__ W = isR ? Wr : Wl;
    const float* __restrict__ rows = hs + g * 8 * 128;
    float4 acc[8];
    #pragma unroll
    for (int r = 0; r < 8; ++r) acc[r] = make_float4(0.f, 0.f, 0.f, 0.f);
    for (int k = 0; k < 128; k += 4) {
        float4 w0 = *(const float4*)(W + (size_t)(k+0) * 64 + col);
        float4 w1 = *(const float4*)(W + (size_t)(k+1) * 64 + col);
        float4 w2 = *(const float4*)(W + (size_t)(k+2) * 64 + col);
        float4 w3 = *(const float4*)(W + (size_t)(k+3) * 64 + col);
        #pragma unroll
        for (int r = 0; r < 8; ++r) {
            float4 xv = *(const float4*)(rows + r * 128 + k);
            fma4(acc[r], xv.x, w0); fma4(acc[r], xv.y, w1);
            fma4(acc[r], xv.z, w2); fma4(acc[r], xv.w, w3);
        }
    }
    const float* __restrict__ bp = isR ? br : bl;
    float4 bv = *(const float4*)(bp + col);
    const int rbase = n0 + g * 8;
    #pragma unroll
    for (int r = 0; r < 8; ++r) {
        int row = rbase + r;
        if (row >= N_) continue;
        float4 v = acc[r];
        v.x += bv.x; v.y += bv.y; v.z += bv.z; v.w += bv.w;
        if (isR) {
            *(float4*)(xr2 + (size_t)row * 64 + col) = v;
        } else {
            uint2 pk;
            pk.x = pack2(v.x, v.y);
            pk.y = pack2(v.z, v.w);
            *(uint2*)(xl2b + (size_t)row * 32 + 2 * tt) = pk;
        }
    }
}

// ====== layer 2 fused attention: one wave per node, TWO edges at a time ======
// (r9/r10/r12-validated)
__global__ __launch_bounds__(256) void fused2(
        const int* __restrict__ csr_src, const int* __restrict__ start,
        const int* __restrict__ count,
        const unsigned* __restrict__ xl2b, const float* __restrict__ xr2,
        const float* __restrict__ att, const float* __restrict__ bias2,
        float* __restrict__ out) {
    int t = blockIdx.x * 256 + threadIdx.x;
    int n = __builtin_amdgcn_readfirstlane(t >> 6);   // wave-uniform node id
    int lane = t & 63;
    int half = lane >> 5;                 // which edge of the pair
    int lc   = lane & 31;                 // channel pair id
    if (n >= N_) return;
    float2 xr = *(const float2*)(xr2 + (size_t)n * 64 + 2 * lc);
    float2 av = *(const float2*)(att + 2 * lc);
    int p0 = __builtin_amdgcn_readfirstlane(start[n]);
    int p1 = p0 + __builtin_amdgcn_readfirstlane(count[n]);
    float2 acc = make_float2(0.f, 0.f);
    float l = 0.f;
    for (int p = p0; p < p1; p += 8) {
        #pragma unroll
        for (int u = 0; u < 4; ++u) {
            int pe = p + 2 * u + half;
            int pc = pe < p1 ? pe : p1 - 1;
            int s  = csr_src[pc];
            float2 xv = unpack2(xl2b[(size_t)s * 32 + lc]);
            float a = fmaf(leaky(xv.x + xr.x), av.x, leaky(xv.y + xr.y) * av.y);
            a += __shfl_xor(a, 1);
            a += __shfl_xor(a, 2);
            a += __shfl_xor(a, 4);
            a += __shfl_xor(a, 8);
            a += __shfl_xor(a, 16);
            float w = pe < p1 ? __expf(a) : 0.f;
            acc.x = fmaf(w, xv.x, acc.x);
            acc.y = fmaf(w, xv.y, acc.y);
            l += w;
        }
    }
    acc.x += __shfl_xor(acc.x, 32);
    acc.y += __shfl_xor(acc.y, 32);
    l     += __shfl_xor(l, 32);
    if (half == 0) {
        float2 bv = *(const float2*)(bias2 + 2 * lc);
        float2 o;
        o.x = acc.x / l + bv.x;
        o.y = acc.y / l + bv.y;
        *(float2*)(out + (size_t)n * 64 + 2 * lc) = o;
    }
}

extern "C" void kernel_launch(void* const* d_in, const int* in_sizes, int n_in,
                              void* d_out, int out_size, void* d_ws, size_t ws_size,
                              hipStream_t stream) {
    (void)in_sizes; (void)n_in; (void)out_size; (void)ws_size;
    const float* x     = (const float*)d_in[0];
    const int*   ei    = (const int*)d_in[1];
    const float* W1l   = (const float*)d_in[2];
    const float* b1l   = (const float*)d_in[3];
    const float* W1r   = (const float*)d_in[4];
    const float* b1r   = (const float*)d_in[5];
    const float* att1  = (const float*)d_in[6];
    const float* bias1 = (const float*)d_in[7];
    const float* W2l   = (const float*)d_in[8];
    const float* b2l   = (const float*)d_in[9];
    const float* W2r   = (const float*)d_in[10];
    const float* b2r   = (const float*)d_in[11];
    const float* att2  = (const float*)d_in[12];
    const float* bias2 = (const float*)d_in[13];
    float* out = (float*)d_out;

    // workspace layout — byte-identical to round 12 (replay-proven).
    float* xr1      = (float*)d_ws;                // 6,400,000 f
    float* hbuf     = xr1 + 6400000;               // 6,400,000 f
    unsigned* xl1b  = (unsigned*)(hbuf + 6400000); // 3,200,000 u (bf16 pairs)
    int* count   = (int*)(xl1b + 3200000);         //    50,000 i
    int* startp  = count + 50000;                  //    50,000 i
    int* off     = startp + 50000;                 //   850,000 i
    int* csr_src = off + 850000;                   //   850,000 i
    int* bsum    = csr_src + 850000;               //       256 i
    int* bstart  = bsum + 256;                     //       256 i
    unsigned* xl2b = xl1b;                         // alias: xl1b dead after fused1
    float* xr2     = xr1;                          // alias: xr1 dead after fused1
    // wsw (64 KB of bf16 W1 fragments) aliases the FRONT of hbuf: hbuf is not
    // written until fused1, and gemm1_mfma (the only wsw reader) runs before.
    unsigned short* wsw = (unsigned short*)hbuf;

    hipMemsetAsync((void*)count, 0, 50000 * sizeof(int), stream);

    const int EB = (ET_ + 255) / 256;
    hist_kernel <<<EB, 256, 0, stream>>>(ei, count, off);
    scan_partial<<<SCAN_NB, 256, 0, stream>>>(count, bsum);
    scan_top    <<<1, 256, 0, stream>>>(bsum, bstart);
    scan_final  <<<SCAN_NB, 256, 0, stream>>>(count, bstart, startp);
    scatter_kernel<<<EB, 256, 0, stream>>>(ei, startp, off, csr_src);

    convert_w <<<128, 256, 0, stream>>>(W1l, W1r, wsw);
    gemm1_mfma<<<N_ / 16, 256, 0, stream>>>(x, wsw, b1l, b1r,
                                            (unsigned short*)xl1b, xr1);
    fused1<<<(N_ * 64 + 255) / 256, 256, 0, stream>>>(csr_src, startp, count,
                                                      xl1b, xr1, att1, bias1, hbuf);

    gemm2 <<<(N_ + 63) / 64, 256, 0, stream>>>(hbuf, W2l, W2r, b2l, b2r, xl2b, xr2);
    fused2<<<(N_ * 64 + 255) / 256, 256, 0, stream>>>(csr_src, startp, count,
                                                      xl2b, xr2, att2, bias2, out);
}

// Round 14
// 274.907 us; speedup vs baseline: 1.2794x; 1.0480x over previous
//
#include <hip/hip_runtime.h>
#include <hip/hip_bf16.h>

// Problem constants
constexpr int N_  = 50000;
constexpr int E_  = 800000;
constexpr int ET_ = 850000;   // edges + self loops
constexpr float NEG_SLOPE = 0.2f;

constexpr int SCAN_NB = (N_ + 255) / 256;   // 196 scan blocks

typedef __attribute__((ext_vector_type(8))) short short8;   // 8 bf16 = 4 VGPRs
typedef __attribute__((ext_vector_type(4))) float f32x4;    // MFMA accumulator

__device__ inline void edge_sd(int e, const int* __restrict__ ei, int& s, int& d) {
    if (e < E_) { s = ei[e]; d = ei[E_ + e]; }
    else        { s = e - E_; d = s; }
}

__device__ inline float leaky(float v) { return fmaxf(v, NEG_SLOPE * v); }

// bf16 round-to-nearest-even (matches __float2bfloat16)
__device__ inline unsigned bf16rn(float f) {
    union { float f; unsigned u; } v; v.f = f;
    return (v.u + 0x7fffu + ((v.u >> 16) & 1u)) >> 16;
}
__device__ inline float2 unpack2(unsigned u) {
    return make_float2(__uint_as_float(u << 16), __uint_as_float(u & 0xffff0000u));
}

// ======================= CSR build (dst-sorted) =======================
__global__ __launch_bounds__(256) void hist_kernel(
        const int* __restrict__ ei, int* __restrict__ count, int* __restrict__ off) {
    int e = blockIdx.x * 256 + threadIdx.x;
    if (e >= ET_) return;
    int s, d; edge_sd(e, ei, s, d);
    off[e] = atomicAdd(&count[d], 1);
}

__global__ __launch_bounds__(256) void scan_partial(
        const int* __restrict__ count, int* __restrict__ bsum) {
    __shared__ int red[256];
    int t = threadIdx.x;
    int i = blockIdx.x * 256 + t;
    red[t] = (i < N_) ? count[i] : 0;
    __syncthreads();
    #pragma unroll
    for (int o = 128; o > 0; o >>= 1) {
        if (t < o) red[t] += red[t + o];
        __syncthreads();
    }
    if (t == 0) bsum[blockIdx.x] = red[0];
}

__global__ __launch_bounds__(256) void scan_top(
        const int* __restrict__ bsum, int* __restrict__ bstart) {
    __shared__ int buf[256];
    int t = threadIdx.x;
    int v = (t < SCAN_NB) ? bsum[t] : 0;
    buf[t] = v;
    __syncthreads();
    #pragma unroll
    for (int o = 1; o < 256; o <<= 1) {
        int add = (t >= o) ? buf[t - o] : 0;
        __syncthreads();
        buf[t] += add;
        __syncthreads();
    }
    if (t < SCAN_NB) bstart[t] = buf[t] - v;   // exclusive
}

__global__ __launch_bounds__(256) void scan_final(
        const int* __restrict__ count, const int* __restrict__ bstart,
        int* __restrict__ start) {
    __shared__ int buf[256];
    int t = threadIdx.x;
    int i = blockIdx.x * 256 + t;
    int v = (i < N_) ? count[i] : 0;
    buf[t] = v;
    __syncthreads();
    #pragma unroll
    for (int o = 1; o < 256; o <<= 1) {
        int add = (t >= o) ? buf[t - o] : 0;
        __syncthreads();
        buf[t] += add;
        __syncthreads();
    }
    if (i < N_) start[i] = bstart[blockIdx.x] + buf[t] - v;
}

__global__ __launch_bounds__(256) void scatter_kernel(
        const int* __restrict__ ei, const int* __restrict__ start,
        const int* __restrict__ off, int* __restrict__ csr_src) {
    int e = blockIdx.x * 256 + threadIdx.x;
    if (e >= ET_) return;
    int s, d; edge_sd(e, ei, s, d);
    csr_src[start[d] + off[e]] = s;
}

// ============ W1 -> B-fragment-swizzled bf16 (64 KB, aliased in hbuf) ============
// wsw[((ct*4+ks)*64 + lane)*8 + j] = bf16(W[k = ks*32 + (lane>>4)*8 + j]
//                                          [c = ct*16 + (lane&15)])
// ct 0..7 -> W1l cols 0..127; ct 8..15 -> W1r cols 0..127.
__global__ __launch_bounds__(256) void convert_w(
        const float* __restrict__ Wl, const float* __restrict__ Wr,
        unsigned short* __restrict__ wsw) {
    int tid = blockIdx.x * 256 + threadIdx.x;   // 0..32767
    if (tid >= 32768) return;
    int j    = tid & 7;
    int lane = (tid >> 3) & 63;
    int ks   = (tid >> 9) & 3;
    int ct   = tid >> 11;
    int k = ks * 32 + ((lane >> 4) & 3) * 8 + j;
    int c = ct * 16 + (lane & 15);
    float v = (c < 128) ? Wl[k * 128 + c] : Wr[k * 128 + (c - 128)];
    wsw[tid] = (unsigned short)bf16rn(v);
}

// ============ W2 -> B-fragment-swizzled bf16 (32 KB, ws tail) ============
// ct 0..3 -> W2l cols 0..63; ct 4..7 -> W2r cols 0..63. W2 is [128 x 64].
__global__ __launch_bounds__(256) void convert_w2(
        const float* __restrict__ Wl, const float* __restrict__ Wr,
        unsigned short* __restrict__ wsw2) {
    int tid = blockIdx.x * 256 + threadIdx.x;   // 0..16383
    if (tid >= 16384) return;
    int j    = tid & 7;
    int lane = (tid >> 3) & 63;
    int ks   = (tid >> 9) & 3;
    int ct   = tid >> 11;                       // 0..7
    int k = ks * 32 + ((lane >> 4) & 3) * 8 + j;
    int c = ct * 16 + (lane & 15);
    float v = (c < 64) ? Wl[k * 64 + c] : Wr[k * 64 + (c - 64)];
    wsw2[tid] = (unsigned short)bf16rn(v);
}

// ======================= layer 1 node transforms (MFMA) =======================
// (r13-validated) Flat grid: 3125 blocks x 256. Each wave: 16 rows x 4 col-tiles.
__global__ __launch_bounds__(256) void gemm1_mfma(
        const float* __restrict__ x,
        const unsigned short* __restrict__ wsw,
        const float* __restrict__ bl, const float* __restrict__ br,
        unsigned short* __restrict__ xlu, float* __restrict__ xr1) {
    const int wave = threadIdx.x >> 6;
    const int lane = threadIdx.x & 63;
    const int n0 = blockIdx.x * 16;
    const int m = lane & 15;
    const int q = (lane >> 4) & 3;
    const float* __restrict__ arow = x + (size_t)(n0 + m) * 128 + q * 8;
    short8 afrag[4];
    #pragma unroll
    for (int ks = 0; ks < 4; ++ks) {
        float4 v0 = *(const float4*)(arow + ks * 32);
        float4 v1 = *(const float4*)(arow + ks * 32 + 4);
        short8 a;
        a[0] = (short)bf16rn(v0.x); a[1] = (short)bf16rn(v0.y);
        a[2] = (short)bf16rn(v0.z); a[3] = (short)bf16rn(v0.w);
        a[4] = (short)bf16rn(v1.x); a[5] = (short)bf16rn(v1.y);
        a[6] = (short)bf16rn(v1.z); a[7] = (short)bf16rn(v1.w);
        afrag[ks] = a;
    }
    #pragma unroll
    for (int i = 0; i < 4; ++i) {
        const int ct = wave * 4 + i;
        f32x4 acc = {0.f, 0.f, 0.f, 0.f};
        #pragma unroll
        for (int ks = 0; ks < 4; ++ks) {
            short8 b = *(const short8*)(wsw + ((size_t)(ct * 4 + ks) * 64 + lane) * 8);
            acc = __builtin_amdgcn_mfma_f32_16x16x32_bf16(afrag[ks], b, acc, 0, 0, 0);
        }
        const int col = ct * 16 + m;
        if (ct < 8) {
            float bias = bl[col];
            #pragma unroll
            for (int j = 0; j < 4; ++j) {
                int row = n0 + q * 4 + j;
                xlu[(size_t)row * 128 + col] = (unsigned short)bf16rn(acc[j] + bias);
            }
        } else {
            float bias = br[col - 128];
            #pragma unroll
            for (int j = 0; j < 4; ++j) {
                int row = n0 + q * 4 + j;
                xr1[(size_t)row * 128 + (col - 128)] = acc[j] + bias;
            }
        }
    }
}

// ====== layer 1 fused attention: ONE wave per node, bf16-pair gathers ======
// (r9/r12/r13-validated) lane owns channels (2l, 2l+1); head = lane>>3.
__global__ __launch_bounds__(256) void fused1(
        const int* __restrict__ csr_src, const int* __restrict__ start,
        const int* __restrict__ count,
        const unsigned* __restrict__ xl1b, const float* __restrict__ xr1,
        const float* __restrict__ att, const float* __restrict__ bias1,
        float* __restrict__ hout) {
    int t = blockIdx.x * 256 + threadIdx.x;
    int n = __builtin_amdgcn_readfirstlane(t >> 6);   // wave-uniform node id
    int lane = t & 63;
    if (n >= N_) return;
    float2 xr = *(const float2*)(xr1 + (size_t)n * 128 + 2 * lane);
    float2 av = *(const float2*)(att + 2 * lane);
    int p0 = __builtin_amdgcn_readfirstlane(start[n]);
    int p1 = p0 + __builtin_amdgcn_readfirstlane(count[n]);
    float2 acc = make_float2(0.f, 0.f);
    float l = 0.f;
    for (int p = p0; p < p1; p += 4) {
        int q1 = p + 1 < p1 ? p + 1 : p1 - 1;
        int q2 = p + 2 < p1 ? p + 2 : p1 - 1;
        int q3 = p + 3 < p1 ? p + 3 : p1 - 1;
        int s0 = __builtin_amdgcn_readfirstlane(csr_src[p]);
        int s1 = __builtin_amdgcn_readfirstlane(csr_src[q1]);
        int s2 = __builtin_amdgcn_readfirstlane(csr_src[q2]);
        int s3 = __builtin_amdgcn_readfirstlane(csr_src[q3]);
        float2 x0 = unpack2(xl1b[(size_t)s0 * 64 + lane]);
        float2 x1 = unpack2(xl1b[(size_t)s1 * 64 + lane]);
        float2 x2 = unpack2(xl1b[(size_t)s2 * 64 + lane]);
        float2 x3 = unpack2(xl1b[(size_t)s3 * 64 + lane]);
        float a0 = fmaf(leaky(x0.x + xr.x), av.x, leaky(x0.y + xr.y) * av.y);
        float a1 = fmaf(leaky(x1.x + xr.x), av.x, leaky(x1.y + xr.y) * av.y);
        float a2 = fmaf(leaky(x2.x + xr.x), av.x, leaky(x2.y + xr.y) * av.y);
        float a3 = fmaf(leaky(x3.x + xr.x), av.x, leaky(x3.y + xr.y) * av.y);
        a0 += __shfl_xor(a0, 1); a1 += __shfl_xor(a1, 1);
        a2 += __shfl_xor(a2, 1); a3 += __shfl_xor(a3, 1);
        a0 += __shfl_xor(a0, 2); a1 += __shfl_xor(a1, 2);
        a2 += __shfl_xor(a2, 2); a3 += __shfl_xor(a3, 2);
        a0 += __shfl_xor(a0, 4); a1 += __shfl_xor(a1, 4);
        a2 += __shfl_xor(a2, 4); a3 += __shfl_xor(a3, 4);
        float w0 = __expf(a0);
        float w1 = p + 1 < p1 ? __expf(a1) : 0.f;
        float w2 = p + 2 < p1 ? __expf(a2) : 0.f;
        float w3 = p + 3 < p1 ? __expf(a3) : 0.f;
        acc.x = fmaf(w0, x0.x, acc.x); acc.y = fmaf(w0, x0.y, acc.y); l += w0;
        acc.x = fmaf(w1, x1.x, acc.x); acc.y = fmaf(w1, x1.y, acc.y); l += w1;
        acc.x = fmaf(w2, x2.x, acc.x); acc.y = fmaf(w2, x2.y, acc.y); l += w2;
        acc.x = fmaf(w3, x3.x, acc.x); acc.y = fmaf(w3, x3.y, acc.y); l += w3;
    }
    float2 bv = *(const float2*)(bias1 + 2 * lane);
    float vx = acc.x / l + bv.x;
    float vy = acc.y / l + bv.y;
    float2 o;
    o.x = vx > 0.f ? vx : (__expf(vx) - 1.f);
    o.y = vy > 0.f ? vy : (__expf(vy) - 1.f);
    *(float2*)(hout + (size_t)n * 128 + 2 * lane) = o;
}

// ======================= layer 2 node transforms (MFMA) =======================
// Same recipe as gemm1_mfma; 8 col-tiles (ct<4 -> xl2b bf16, else xr2 f32);
// each of the 4 waves handles 2 col-tiles; A = hbuf rows, bf16 in-register.
__global__ __launch_bounds__(256) void gemm2_mfma(
        const float* __restrict__ hbuf,
        const unsigned short* __restrict__ wsw2,
        const float* __restrict__ bl, const float* __restrict__ br,
        unsigned short* __restrict__ xlu2, float* __restrict__ xr2) {
    const int wave = threadIdx.x >> 6;
    const int lane = threadIdx.x & 63;
    const int n0 = blockIdx.x * 16;
    const int m = lane & 15;
    const int q = (lane >> 4) & 3;
    const float* __restrict__ arow = hbuf + (size_t)(n0 + m) * 128 + q * 8;
    short8 afrag[4];
    #pragma unroll
    for (int ks = 0; ks < 4; ++ks) {
        float4 v0 = *(const float4*)(arow + ks * 32);
        float4 v1 = *(const float4*)(arow + ks * 32 + 4);
        short8 a;
        a[0] = (short)bf16rn(v0.x); a[1] = (short)bf16rn(v0.y);
        a[2] = (short)bf16rn(v0.z); a[3] = (short)bf16rn(v0.w);
        a[4] = (short)bf16rn(v1.x); a[5] = (short)bf16rn(v1.y);
        a[6] = (short)bf16rn(v1.z); a[7] = (short)bf16rn(v1.w);
        afrag[ks] = a;
    }
    #pragma unroll
    for (int i = 0; i < 2; ++i) {
        const int ct = wave * 2 + i;
        f32x4 acc = {0.f, 0.f, 0.f, 0.f};
        #pragma unroll
        for (int ks = 0; ks < 4; ++ks) {
            short8 b = *(const short8*)(wsw2 + ((size_t)(ct * 4 + ks) * 64 + lane) * 8);
            acc = __builtin_amdgcn_mfma_f32_16x16x32_bf16(afrag[ks], b, acc, 0, 0, 0);
        }
        const int col = ct * 16 + m;
        if (ct < 4) {
            float bias = bl[col];
            #pragma unroll
            for (int j = 0; j < 4; ++j) {
                int row = n0 + q * 4 + j;
                xlu2[(size_t)row * 64 + col] = (unsigned short)bf16rn(acc[j] + bias);
            }
        } else {
            float bias = br[col - 64];
            #pragma unroll
            for (int j = 0; j < 4; ++j) {
                int row = n0 + q * 4 + j;
                xr2[(size_t)row * 64 + (col - 64)] = acc[j] + bias;
            }
        }
    }
}

// ====== layer 2 fused attention: one wave per node, TWO edges at a time ======
// (r9/r12/r13-validated)
__global__ __launch_bounds__(256) void fused2(
        const int* __restrict__ csr_src, const int* __restrict__ start,
        const int* __restrict__ count,
        const unsigned* __restrict__ xl2b, const float* __restrict__ xr2,
        const float* __restrict__ att, const float* __restrict__ bias2,
        float* __restrict__ out) {
    int t = blockIdx.x * 256 + threadIdx.x;
    int n = __builtin_amdgcn_readfirstlane(t >> 6);   // wave-uniform node id
    int lane = t & 63;
    int half = lane >> 5;                 // which edge of the pair
    int lc   = lane & 31;                 // channel pair id
    if (n >= N_) return;
    float2 xr = *(const float2*)(xr2 + (size_t)n * 64 + 2 * lc);
    float2 av = *(const float2*)(att + 2 * lc);
    int p0 = __builtin_amdgcn_readfirstlane(start[n]);
    int p1 = p0 + __builtin_amdgcn_readfirstlane(count[n]);
    float2 acc = make_float2(0.f, 0.f);
    float l = 0.f;
    for (int p = p0; p < p1; p += 8) {
        #pragma unroll
        for (int u = 0; u < 4; ++u) {
            int pe = p + 2 * u + half;
            int pc = pe < p1 ? pe : p1 - 1;
            int s  = csr_src[pc];
            float2 xv = unpack2(xl2b[(size_t)s * 32 + lc]);
            float a = fmaf(leaky(xv.x + xr.x), av.x, leaky(xv.y + xr.y) * av.y);
            a += __shfl_xor(a, 1);
            a += __shfl_xor(a, 2);
            a += __shfl_xor(a, 4);
            a += __shfl_xor(a, 8);
            a += __shfl_xor(a, 16);
            float w = pe < p1 ? __expf(a) : 0.f;
            acc.x = fmaf(w, xv.x, acc.x);
            acc.y = fmaf(w, xv.y, acc.y);
            l += w;
        }
    }
    acc.x += __shfl_xor(acc.x, 32);
    acc.y += __shfl_xor(acc.y, 32);
    l     += __shfl_xor(l, 32);
    if (half == 0) {
        float2 bv = *(const float2*)(bias2 + 2 * lc);
        float2 o;
        o.x = acc.x / l + bv.x;
        o.y = acc.y / l + bv.y;
        *(float2*)(out + (size_t)n * 64 + 2 * lc) = o;
    }
}

extern "C" void kernel_launch(void* const* d_in, const int* in_sizes, int n_in,
                              void* d_out, int out_size, void* d_ws, size_t ws_size,
                              hipStream_t stream) {
    (void)in_sizes; (void)n_in; (void)out_size; (void)ws_size;
    const float* x     = (const float*)d_in[0];
    const int*   ei    = (const int*)d_in[1];
    const float* W1l   = (const float*)d_in[2];
    const float* b1l   = (const float*)d_in[3];
    const float* W1r   = (const float*)d_in[4];
    const float* b1r   = (const float*)d_in[5];
    const float* att1  = (const float*)d_in[6];
    const float* bias1 = (const float*)d_in[7];
    const float* W2l   = (const float*)d_in[8];
    const float* b2l   = (const float*)d_in[9];
    const float* W2r   = (const float*)d_in[10];
    const float* b2r   = (const float*)d_in[11];
    const float* att2  = (const float*)d_in[12];
    const float* bias2 = (const float*)d_in[13];
    float* out = (float*)d_out;

    // workspace layout — r12/r13 base + 32 KB tail for W2 fragments.
    float* xr1      = (float*)d_ws;                // 6,400,000 f
    float* hbuf     = xr1 + 6400000;               // 6,400,000 f
    unsigned* xl1b  = (unsigned*)(hbuf + 6400000); // 3,200,000 u (bf16 pairs)
    int* count   = (int*)(xl1b + 3200000);         //    50,000 i
    int* startp  = count + 50000;                  //    50,000 i
    int* off     = startp + 50000;                 //   850,000 i
    int* csr_src = off + 850000;                   //   850,000 i
    int* bsum    = csr_src + 850000;               //       256 i
    int* bstart  = bsum + 256;                     //       256 i
    unsigned short* wsw2 = (unsigned short*)(bstart + 256);  // 16,384 bf16 (32 KB)
    unsigned* xl2b = xl1b;                         // alias: xl1b dead after fused1
    float* xr2     = xr1;                          // alias: xr1 dead after fused1
    // wsw1 (64 KB of bf16 W1 fragments) aliases the FRONT of hbuf: hbuf is not
    // written until fused1, and gemm1_mfma (the only reader) runs before.
    unsigned short* wsw = (unsigned short*)hbuf;

    hipMemsetAsync((void*)count, 0, 50000 * sizeof(int), stream);

    const int EB = (ET_ + 255) / 256;
    hist_kernel <<<EB, 256, 0, stream>>>(ei, count, off);
    scan_partial<<<SCAN_NB, 256, 0, stream>>>(count, bsum);
    scan_top    <<<1, 256, 0, stream>>>(bsum, bstart);
    scan_final  <<<SCAN_NB, 256, 0, stream>>>(count, bstart, startp);
    scatter_kernel<<<EB, 256, 0, stream>>>(ei, startp, off, csr_src);

    convert_w  <<<128, 256, 0, stream>>>(W1l, W1r, wsw);
    convert_w2 <<<64, 256, 0, stream>>>(W2l, W2r, wsw2);
    gemm1_mfma <<<N_ / 16, 256, 0, stream>>>(x, wsw, b1l, b1r,
                                             (unsigned short*)xl1b, xr1);
    fused1<<<(N_ * 64 + 255) / 256, 256, 0, stream>>>(csr_src, startp, count,
                                                      xl1b, xr1, att1, bias1, hbuf);

    gemm2_mfma <<<N_ / 16, 256, 0, stream>>>(hbuf, wsw2, b2l, b2r,
                                             (unsigned short*)xl2b, xr2);
    fused2<<<(N_ * 64 + 255) / 256, 256, 0, stream>>>(csr_src, startp, count,
                                                      xl2b, xr2, att2, bias2, out);
}

// Round 15
// 272.837 us; speedup vs baseline: 1.2891x; 1.0076x over previous
//
#include <hip/hip_runtime.h>
#include <hip/hip_bf16.h>

// Problem constants
constexpr int N_  = 50000;
constexpr int E_  = 800000;
constexpr int ET_ = 850000;   // edges + self loops
constexpr float NEG_SLOPE = 0.2f;

constexpr int SCAN_NB = (N_ + 255) / 256;   // 196 scan blocks
constexpr int CSR_CAP = 1250008;            // sum ceil8(count) <= 850K+400K, +8 slack

typedef __attribute__((ext_vector_type(8))) short short8;   // 8 bf16 = 4 VGPRs
typedef __attribute__((ext_vector_type(4))) float f32x4;    // MFMA accumulator

__device__ inline float leaky(float v) { return fmaxf(v, NEG_SLOPE * v); }

// bf16 round-to-nearest-even (matches __float2bfloat16)
__device__ inline unsigned bf16rn(float f) {
    union { float f; unsigned u; } v; v.f = f;
    return (v.u + 0x7fffu + ((v.u >> 16) & 1u)) >> 16;
}
__device__ inline float2 unpack2(unsigned u) {
    return make_float2(__uint_as_float(u << 16), __uint_as_float(u & 0xffff0000u));
}

// ======================= CSR build (dst-sorted, 8-aligned segments) =======================
__global__ __launch_bounds__(256) void hist_kernel(
        const int* __restrict__ ei, int* __restrict__ count, int* __restrict__ off) {
    int e = blockIdx.x * 256 + threadIdx.x;
    if (e >= ET_) return;
    int d = (e < E_) ? ei[E_ + e] : e - E_;
    off[e] = atomicAdd(&count[d], 1);
}

// scan over ceil8(count): start[] offsets are 8-aligned per node
__global__ __launch_bounds__(256) void scan_partial(
        const int* __restrict__ count, int* __restrict__ bsum) {
    __shared__ int red[256];
    int t = threadIdx.x;
    int i = blockIdx.x * 256 + t;
    red[t] = (i < N_) ? ((count[i] + 7) & ~7) : 0;
    __syncthreads();
    #pragma unroll
    for (int o = 128; o > 0; o >>= 1) {
        if (t < o) red[t] += red[t + o];
        __syncthreads();
    }
    if (t == 0) bsum[blockIdx.x] = red[0];
}

__global__ __launch_bounds__(256) void scan_top(
        const int* __restrict__ bsum, int* __restrict__ bstart) {
    __shared__ int buf[256];
    int t = threadIdx.x;
    int v = (t < SCAN_NB) ? bsum[t] : 0;
    buf[t] = v;
    __syncthreads();
    #pragma unroll
    for (int o = 1; o < 256; o <<= 1) {
        int add = (t >= o) ? buf[t - o] : 0;
        __syncthreads();
        buf[t] += add;
        __syncthreads();
    }
    if (t < SCAN_NB) bstart[t] = buf[t] - v;   // exclusive
}

__global__ __launch_bounds__(256) void scan_final(
        const int* __restrict__ count, const int* __restrict__ bstart,
        int* __restrict__ start) {
    __shared__ int buf[256];
    int t = threadIdx.x;
    int i = blockIdx.x * 256 + t;
    int v = (i < N_) ? ((count[i] + 7) & ~7) : 0;
    buf[t] = v;
    __syncthreads();
    #pragma unroll
    for (int o = 1; o < 256; o <<= 1) {
        int add = (t >= o) ? buf[t - o] : 0;
        __syncthreads();
        buf[t] += add;
        __syncthreads();
    }
    if (i < N_) start[i] = bstart[blockIdx.x] + buf[t] - v;
}

__global__ __launch_bounds__(256) void scatter_kernel(
        const int* __restrict__ ei, const int* __restrict__ start,
        const int* __restrict__ off, int* __restrict__ csr_src) {
    int e = blockIdx.x * 256 + threadIdx.x;
    if (e >= ET_) return;
    int s, d;
    if (e < E_) { s = ei[e]; d = ei[E_ + e]; }
    else        { s = e - E_; d = s; }
    csr_src[start[d] + off[e]] = s;
}

// ============ W1 + W2 -> B-fragment-swizzled bf16 (one kernel) ============
// layout per tile-group: frag[((ct*4+ks)*64 + lane)*8 + j] =
//   bf16(W[k = ks*32 + (lane>>4)*8 + j][c = ct*16 + (lane&15)])
__global__ __launch_bounds__(256) void convert_w_all(
        const float* __restrict__ W1l, const float* __restrict__ W1r,
        const float* __restrict__ W2l, const float* __restrict__ W2r,
        unsigned short* __restrict__ wsw, unsigned short* __restrict__ wsw2) {
    int tid = blockIdx.x * 256 + threadIdx.x;   // 0..49151
    if (tid >= 49152) return;
    if (tid < 32768) {
        int j    = tid & 7;
        int lane = (tid >> 3) & 63;
        int ks   = (tid >> 9) & 3;
        int ct   = tid >> 11;
        int k = ks * 32 + ((lane >> 4) & 3) * 8 + j;
        int c = ct * 16 + (lane & 15);
        float v = (c < 128) ? W1l[k * 128 + c] : W1r[k * 128 + (c - 128)];
        wsw[tid] = (unsigned short)bf16rn(v);
    } else {
        int t2   = tid - 32768;                 // 0..16383
        int j    = t2 & 7;
        int lane = (t2 >> 3) & 63;
        int ks   = (t2 >> 9) & 3;
        int ct   = t2 >> 11;                    // 0..7
        int k = ks * 32 + ((lane >> 4) & 3) * 8 + j;
        int c = ct * 16 + (lane & 15);
        float v = (c < 64) ? W2l[k * 64 + c] : W2r[k * 64 + (c - 64)];
        wsw2[t2] = (unsigned short)bf16rn(v);
    }
}

// ======================= layer 1 node transforms (MFMA) =======================
// (r13/r14-validated) Flat grid: 3125 blocks x 256. Wave: 16 rows x 4 col-tiles.
__global__ __launch_bounds__(256) void gemm1_mfma(
        const float* __restrict__ x,
        const unsigned short* __restrict__ wsw,
        const float* __restrict__ bl, const float* __restrict__ br,
        unsigned short* __restrict__ xlu, float* __restrict__ xr1) {
    const int wave = threadIdx.x >> 6;
    const int lane = threadIdx.x & 63;
    const int n0 = blockIdx.x * 16;
    const int m = lane & 15;
    const int q = (lane >> 4) & 3;
    const float* __restrict__ arow = x + (size_t)(n0 + m) * 128 + q * 8;
    short8 afrag[4];
    #pragma unroll
    for (int ks = 0; ks < 4; ++ks) {
        float4 v0 = *(const float4*)(arow + ks * 32);
        float4 v1 = *(const float4*)(arow + ks * 32 + 4);
        short8 a;
        a[0] = (short)bf16rn(v0.x); a[1] = (short)bf16rn(v0.y);
        a[2] = (short)bf16rn(v0.z); a[3] = (short)bf16rn(v0.w);
        a[4] = (short)bf16rn(v1.x); a[5] = (short)bf16rn(v1.y);
        a[6] = (short)bf16rn(v1.z); a[7] = (short)bf16rn(v1.w);
        afrag[ks] = a;
    }
    #pragma unroll
    for (int i = 0; i < 4; ++i) {
        const int ct = wave * 4 + i;
        f32x4 acc = {0.f, 0.f, 0.f, 0.f};
        #pragma unroll
        for (int ks = 0; ks < 4; ++ks) {
            short8 b = *(const short8*)(wsw + ((size_t)(ct * 4 + ks) * 64 + lane) * 8);
            acc = __builtin_amdgcn_mfma_f32_16x16x32_bf16(afrag[ks], b, acc, 0, 0, 0);
        }
        const int col = ct * 16 + m;
        if (ct < 8) {
            float bias = bl[col];
            #pragma unroll
            for (int j = 0; j < 4; ++j) {
                int row = n0 + q * 4 + j;
                xlu[(size_t)row * 128 + col] = (unsigned short)bf16rn(acc[j] + bias);
            }
        } else {
            float bias = br[col - 128];
            #pragma unroll
            for (int j = 0; j < 4; ++j) {
                int row = n0 + q * 4 + j;
                xr1[(size_t)row * 128 + (col - 128)] = acc[j] + bias;
            }
        }
    }
}

// ====== layer 1 fused attention: ONE wave per node, bf16-pair gathers ======
// 8-aligned zero-padded CSR: indices load as one aligned uniform int4
// (scalar-pipe eligible); pad slots gather node 0, masked by w=0.
__global__ __launch_bounds__(256) void fused1(
        const int* __restrict__ csr_src, const int* __restrict__ start,
        const int* __restrict__ count,
        const unsigned* __restrict__ xl1b, const float* __restrict__ xr1,
        const float* __restrict__ att, const float* __restrict__ bias1,
        float* __restrict__ hout) {
    int t = blockIdx.x * 256 + threadIdx.x;
    int n = __builtin_amdgcn_readfirstlane(t >> 6);   // wave-uniform node id
    int lane = t & 63;
    if (n >= N_) return;
    float2 xr = *(const float2*)(xr1 + (size_t)n * 128 + 2 * lane);
    float2 av = *(const float2*)(att + 2 * lane);
    int p0 = __builtin_amdgcn_readfirstlane(start[n]);
    int p1 = p0 + __builtin_amdgcn_readfirstlane(count[n]);
    float2 acc = make_float2(0.f, 0.f);
    float l = 0.f;
    for (int p = p0; p < p1; p += 4) {
        int4 si = *(const int4*)(csr_src + p);         // uniform, 16B-aligned
        int s0 = __builtin_amdgcn_readfirstlane(si.x);
        int s1 = __builtin_amdgcn_readfirstlane(si.y);
        int s2 = __builtin_amdgcn_readfirstlane(si.z);
        int s3 = __builtin_amdgcn_readfirstlane(si.w);
        float2 x0 = unpack2(xl1b[(size_t)s0 * 64 + lane]);
        float2 x1 = unpack2(xl1b[(size_t)s1 * 64 + lane]);
        float2 x2 = unpack2(xl1b[(size_t)s2 * 64 + lane]);
        float2 x3 = unpack2(xl1b[(size_t)s3 * 64 + lane]);
        float a0 = fmaf(leaky(x0.x + xr.x), av.x, leaky(x0.y + xr.y) * av.y);
        float a1 = fmaf(leaky(x1.x + xr.x), av.x, leaky(x1.y + xr.y) * av.y);
        float a2 = fmaf(leaky(x2.x + xr.x), av.x, leaky(x2.y + xr.y) * av.y);
        float a3 = fmaf(leaky(x3.x + xr.x), av.x, leaky(x3.y + xr.y) * av.y);
        a0 += __shfl_xor(a0, 1); a1 += __shfl_xor(a1, 1);
        a2 += __shfl_xor(a2, 1); a3 += __shfl_xor(a3, 1);
        a0 += __shfl_xor(a0, 2); a1 += __shfl_xor(a1, 2);
        a2 += __shfl_xor(a2, 2); a3 += __shfl_xor(a3, 2);
        a0 += __shfl_xor(a0, 4); a1 += __shfl_xor(a1, 4);
        a2 += __shfl_xor(a2, 4); a3 += __shfl_xor(a3, 4);
        float w0 = __expf(a0);
        float w1 = p + 1 < p1 ? __expf(a1) : 0.f;
        float w2 = p + 2 < p1 ? __expf(a2) : 0.f;
        float w3 = p + 3 < p1 ? __expf(a3) : 0.f;
        acc.x = fmaf(w0, x0.x, acc.x); acc.y = fmaf(w0, x0.y, acc.y); l += w0;
        acc.x = fmaf(w1, x1.x, acc.x); acc.y = fmaf(w1, x1.y, acc.y); l += w1;
        acc.x = fmaf(w2, x2.x, acc.x); acc.y = fmaf(w2, x2.y, acc.y); l += w2;
        acc.x = fmaf(w3, x3.x, acc.x); acc.y = fmaf(w3, x3.y, acc.y); l += w3;
    }
    float2 bv = *(const float2*)(bias1 + 2 * lane);
    float vx = acc.x / l + bv.x;
    float vy = acc.y / l + bv.y;
    float2 o;
    o.x = vx > 0.f ? vx : (__expf(vx) - 1.f);
    o.y = vy > 0.f ? vy : (__expf(vy) - 1.f);
    *(float2*)(hout + (size_t)n * 128 + 2 * lane) = o;
}

// ======================= layer 2 node transforms (MFMA) =======================
// (r14-validated) 8 col-tiles (ct<4 -> xl2b bf16, else xr2 f32); 2 tiles/wave.
__global__ __launch_bounds__(256) void gemm2_mfma(
        const float* __restrict__ hbuf,
        const unsigned short* __restrict__ wsw2,
        const float* __restrict__ bl, const float* __restrict__ br,
        unsigned short* __restrict__ xlu2, float* __restrict__ xr2) {
    const int wave = threadIdx.x >> 6;
    const int lane = threadIdx.x & 63;
    const int n0 = blockIdx.x * 16;
    const int m = lane & 15;
    const int q = (lane >> 4) & 3;
    const float* __restrict__ arow = hbuf + (size_t)(n0 + m) * 128 + q * 8;
    short8 afrag[4];
    #pragma unroll
    for (int ks = 0; ks < 4; ++ks) {
        float4 v0 = *(const float4*)(arow + ks * 32);
        float4 v1 = *(const float4*)(arow + ks * 32 + 4);
        short8 a;
        a[0] = (short)bf16rn(v0.x); a[1] = (short)bf16rn(v0.y);
        a[2] = (short)bf16rn(v0.z); a[3] = (short)bf16rn(v0.w);
        a[4] = (short)bf16rn(v1.x); a[5] = (short)bf16rn(v1.y);
        a[6] = (short)bf16rn(v1.z); a[7] = (short)bf16rn(v1.w);
        afrag[ks] = a;
    }
    #pragma unroll
    for (int i = 0; i < 2; ++i) {
        const int ct = wave * 2 + i;
        f32x4 acc = {0.f, 0.f, 0.f, 0.f};
        #pragma unroll
        for (int ks = 0; ks < 4; ++ks) {
            short8 b = *(const short8*)(wsw2 + ((size_t)(ct * 4 + ks) * 64 + lane) * 8);
            acc = __builtin_amdgcn_mfma_f32_16x16x32_bf16(afrag[ks], b, acc, 0, 0, 0);
        }
        const int col = ct * 16 + m;
        if (ct < 4) {
            float bias = bl[col];
            #pragma unroll
            for (int j = 0; j < 4; ++j) {
                int row = n0 + q * 4 + j;
                xlu2[(size_t)row * 64 + col] = (unsigned short)bf16rn(acc[j] + bias);
            }
        } else {
            float bias = br[col - 64];
            #pragma unroll
            for (int j = 0; j < 4; ++j) {
                int row = n0 + q * 4 + j;
                xr2[(size_t)row * 64 + (col - 64)] = acc[j] + bias;
            }
        }
    }
}

// ====== layer 2 fused attention: one wave per node, TWO edges at a time ======
// 8-aligned zero-padded CSR: two aligned uniform int4 index loads per iter.
__global__ __launch_bounds__(256) void fused2(
        const int* __restrict__ csr_src, const int* __restrict__ start,
        const int* __restrict__ count,
        const unsigned* __restrict__ xl2b, const float* __restrict__ xr2,
        const float* __restrict__ att, const float* __restrict__ bias2,
        float* __restrict__ out) {
    int t = blockIdx.x * 256 + threadIdx.x;
    int n = __builtin_amdgcn_readfirstlane(t >> 6);   // wave-uniform node id
    int lane = t & 63;
    int half = lane >> 5;                 // which edge of the pair
    int lc   = lane & 31;                 // channel pair id
    if (n >= N_) return;
    float2 xr = *(const float2*)(xr2 + (size_t)n * 64 + 2 * lc);
    float2 av = *(const float2*)(att + 2 * lc);
    int p0 = __builtin_amdgcn_readfirstlane(start[n]);
    int p1 = p0 + __builtin_amdgcn_readfirstlane(count[n]);
    float2 acc = make_float2(0.f, 0.f);
    float l = 0.f;
    for (int p = p0; p < p1; p += 8) {
        int4 ia = *(const int4*)(csr_src + p);         // uniform, aligned
        int4 ib = *(const int4*)(csr_src + p + 4);
        int sx[8];
        sx[0] = __builtin_amdgcn_readfirstlane(ia.x);
        sx[1] = __builtin_amdgcn_readfirstlane(ia.y);
        sx[2] = __builtin_amdgcn_readfirstlane(ia.z);
        sx[3] = __builtin_amdgcn_readfirstlane(ia.w);
        sx[4] = __builtin_amdgcn_readfirstlane(ib.x);
        sx[5] = __builtin_amdgcn_readfirstlane(ib.y);
        sx[6] = __builtin_amdgcn_readfirstlane(ib.z);
        sx[7] = __builtin_amdgcn_readfirstlane(ib.w);
        #pragma unroll
        for (int u = 0; u < 4; ++u) {
            int pe = p + 2 * u + half;
            int s  = sx[2 * u + half];
            float2 xv = unpack2(xl2b[(size_t)s * 32 + lc]);
            float a = fmaf(leaky(xv.x + xr.x), av.x, leaky(xv.y + xr.y) * av.y);
            a += __shfl_xor(a, 1);
            a += __shfl_xor(a, 2);
            a += __shfl_xor(a, 4);
            a += __shfl_xor(a, 8);
            a += __shfl_xor(a, 16);
            float w = pe < p1 ? __expf(a) : 0.f;
            acc.x = fmaf(w, xv.x, acc.x);
            acc.y = fmaf(w, xv.y, acc.y);
            l += w;
        }
    }
    acc.x += __shfl_xor(acc.x, 32);
    acc.y += __shfl_xor(acc.y, 32);
    l     += __shfl_xor(l, 32);
    if (half == 0) {
        float2 bv = *(const float2*)(bias2 + 2 * lc);
        float2 o;
        o.x = acc.x / l + bv.x;
        o.y = acc.y / l + bv.y;
        *(float2*)(out + (size_t)n * 64 + 2 * lc) = o;
    }
}

extern "C" void kernel_launch(void* const* d_in, const int* in_sizes, int n_in,
                              void* d_out, int out_size, void* d_ws, size_t ws_size,
                              hipStream_t stream) {
    (void)in_sizes; (void)n_in; (void)out_size; (void)ws_size;
    const float* x     = (const float*)d_in[0];
    const int*   ei    = (const int*)d_in[1];
    const float* W1l   = (const float*)d_in[2];
    const float* b1l   = (const float*)d_in[3];
    const float* W1r   = (const float*)d_in[4];
    const float* b1r   = (const float*)d_in[5];
    const float* att1  = (const float*)d_in[6];
    const float* bias1 = (const float*)d_in[7];
    const float* W2l   = (const float*)d_in[8];
    const float* b2l   = (const float*)d_in[9];
    const float* W2r   = (const float*)d_in[10];
    const float* b2r   = (const float*)d_in[11];
    const float* att2  = (const float*)d_in[12];
    const float* bias2 = (const float*)d_in[13];
    float* out = (float*)d_out;

    // workspace layout. count and csr_src are contiguous so ONE memset zeroes
    // both (csr pad slots must be 0 every call — replay re-poisons ws).
    float* xr1      = (float*)d_ws;                // 6,400,000 f
    float* hbuf     = xr1 + 6400000;               // 6,400,000 f
    unsigned* xl1b  = (unsigned*)(hbuf + 6400000); // 3,200,000 u (bf16 pairs)
    int* count   = (int*)(xl1b + 3200000);         //    50,000 i
    int* csr_src = count + 50000;                  // 1,250,008 i (8-aligned segs)
    int* startp  = csr_src + CSR_CAP;              //    50,000 i
    int* off     = startp + 50000;                 //   850,000 i
    int* bsum    = off + 850000;                   //       256 i
    int* bstart  = bsum + 256;                     //       256 i
    unsigned short* wsw2 = (unsigned short*)(bstart + 256);  // 16,384 bf16 (32 KB)
    unsigned* xl2b = xl1b;                         // alias: xl1b dead after fused1
    float* xr2     = xr1;                          // alias: xr1 dead after fused1
    // wsw1 (64 KB of bf16 W1 fragments) aliases the FRONT of hbuf: hbuf is not
    // written until fused1, and gemm1_mfma (the only reader) runs before.
    unsigned short* wsw = (unsigned short*)hbuf;

    hipMemsetAsync((void*)count, 0, (size_t)(50000 + CSR_CAP) * 4, stream);

    const int EB = (ET_ + 255) / 256;
    hist_kernel <<<EB, 256, 0, stream>>>(ei, count, off);
    scan_partial<<<SCAN_NB, 256, 0, stream>>>(count, bsum);
    scan_top    <<<1, 256, 0, stream>>>(bsum, bstart);
    scan_final  <<<SCAN_NB, 256, 0, stream>>>(count, bstart, startp);
    scatter_kernel<<<EB, 256, 0, stream>>>(ei, startp, off, csr_src);

    convert_w_all<<<192, 256, 0, stream>>>(W1l, W1r, W2l, W2r, wsw, wsw2);
    gemm1_mfma <<<N_ / 16, 256, 0, stream>>>(x, wsw, b1l, b1r,
                                             (unsigned short*)xl1b, xr1);
    fused1<<<(N_ * 64 + 255) / 256, 256, 0, stream>>>(csr_src, startp, count,
                                                      xl1b, xr1, att1, bias1, hbuf);

    gemm2_mfma <<<N_ / 16, 256, 0, stream>>>(hbuf, wsw2, b2l, b2r,
                                             (unsigned short*)xl2b, xr2);
    fused2<<<(N_ * 64 + 255) / 256, 256, 0, stream>>>(csr_src, startp, count,
                                                      xl2b, xr2, att2, bias2, out);
}